// Round 13
// baseline (395.909 us; speedup 1.0000x reference)
//
#include <hip/hip_runtime.h>
#include <hip/hip_bf16.h>

#define NPTS 65536
#define LOGN 16
#define KNB 16
#define NEGS 0.2f
#define EPSV 1e-5f

// GN stages
#define ST_MLP1 0
#define ST_SKIP 1
#define ST_L1   2
#define ST_M1   3
#define ST_L2   4
#define ST_M2   5
#define ST_OUT  6

// ws layout (floats): raw stats | fin | recA (32B/pt) | recB (32B/pt) | prem2 | pairbuf
// recA: [pre1 bf16x8 (16B)][xyz f32x3 (12B)][pad]   -- gathered by k1,k2
// recB: [prem1 bf16x8 (16B)][xyz f32x3 (12B)][pad]  -- gathered by k3
// pairbuf: bf16x8 per (point,neighbor) pair. k1 writes l1pre; k2 reads l1pre
//          then overwrites the SAME slot with l2pre; k3 reads l2pre.
#define STAT_F   14336                       // 7*4*4*128
#define FIN_OFF  14336
#define RECA_OFF 16384
#define RECB_OFF  (RECA_OFF + 4*NPTS*8)
#define PREM2_OFF (RECB_OFF + 4*NPTS*8)
#define PAIR_OFF  (PREM2_OFF + 4*NPTS*16)
#define PAIR_FLOATS ((size_t)4*NPTS*KNB*4)
#define NEED_BYTES (((size_t)PAIR_OFF + PAIR_FLOATS)*4)

typedef __attribute__((ext_vector_type(8))) short short8;
typedef __attribute__((ext_vector_type(4))) float f32x4;
typedef __attribute__((ext_vector_type(4))) unsigned u32x4;

union U16 { uint4 u; short8 s; };

__device__ __forceinline__ float lrelu(float v){ return fmaxf(v, v*NEGS); }

#if defined(__has_builtin)
#  if __has_builtin(__builtin_amdgcn_permlane32_swap)
#    define HAVE_PL32 1
#  endif
#  if __has_builtin(__builtin_amdgcn_permlane16_swap)
#    define HAVE_PL16 1
#  endif
#endif

// cross-lane over lane^16 / lane^32: VALU permlane swaps (no LDS pipe).
__device__ __forceinline__ float s16(float v){
#ifdef HAVE_PL16
  unsigned u = __builtin_bit_cast(unsigned, v);
  auto r = __builtin_amdgcn_permlane16_swap(u, u, false, false);
  return __builtin_bit_cast(float,(unsigned)r[0]) + __builtin_bit_cast(float,(unsigned)r[1]);
#else
  return v + __shfl_xor(v,16);
#endif
}
__device__ __forceinline__ float s32(float v){
#ifdef HAVE_PL32
  unsigned u = __builtin_bit_cast(unsigned, v);
  auto r = __builtin_amdgcn_permlane32_swap(u, u, false, false);
  return __builtin_bit_cast(float,(unsigned)r[0]) + __builtin_bit_cast(float,(unsigned)r[1]);
#else
  return v + __shfl_xor(v,32);
#endif
}
__device__ __forceinline__ float x16max(float v){
#ifdef HAVE_PL16
  unsigned u = __builtin_bit_cast(unsigned, v);
  auto r = __builtin_amdgcn_permlane16_swap(u, u, false, false);
  return fmaxf(__builtin_bit_cast(float,(unsigned)r[0]), __builtin_bit_cast(float,(unsigned)r[1]));
#else
  return fmaxf(v, __shfl_xor(v,16));
#endif
}
__device__ __forceinline__ float x32max(float v){
#ifdef HAVE_PL32
  unsigned u = __builtin_bit_cast(unsigned, v);
  auto r = __builtin_amdgcn_permlane32_swap(u, u, false, false);
  return fmaxf(__builtin_bit_cast(float,(unsigned)r[0]), __builtin_bit_cast(float,(unsigned)r[1]));
#else
  return fmaxf(v, __shfl_xor(v,32));
#endif
}

__device__ __forceinline__ float wred(float v){
  v += __shfl_xor(v,1); v += __shfl_xor(v,2); v += __shfl_xor(v,4); v += __shfl_xor(v,8);
  v = s16(v); return s32(v);
}

__device__ __forceinline__ void wave_fence(){
  __builtin_amdgcn_sched_barrier(0);
  asm volatile("s_waitcnt lgkmcnt(0)" ::: "memory");
  __builtin_amdgcn_sched_barrier(0);
}

__device__ __forceinline__ void load_fin(const float* fin, int stage, int b, int c,
                                         float& sc, float& sh){
  const float* fp = fin + ((stage*4+b)*32 + c)*2;
  sc = fp[0]; sh = fp[1];
}

__device__ __forceinline__ unsigned pkbf(float a, float b){
  __hip_bfloat162 h = __float22bfloat162_rn(make_float2(a,b));
  union{ __hip_bfloat162 h2; unsigned u; } cv; cv.h2 = h; return cv.u;
}
__device__ __forceinline__ float blo(unsigned d){ return __builtin_bit_cast(float, d<<16); }
__device__ __forceinline__ float bhi(unsigned d){ return __builtin_bit_cast(float, d & 0xffff0000u); }
__device__ __forceinline__ float bfu(unsigned short h){ return __builtin_bit_cast(float, ((unsigned)h)<<16); }

// XB row address swizzle: rows 8-15 get bit5 flipped -> PV q-groups hit disjoint banks
__device__ __forceinline__ int rowadr(int row){ return (row*16) ^ ((row&8)<<2); }

// per-wave LDS region: XB planes (2 x 1024B) + AG (256B)
#define XB_OFF 0
#define AG_OFF 2048
#define WV_BYTES 2304

// batch<->XCD affinity decode: bid%8 = XCD (round-robin dispatch heuristic)
__device__ __forceinline__ void xcd_map(int bid, int& b, int& nblk){
  int xcd = bid & 7;
  b = xcd >> 1;
  nblk = ((bid >> 3) << 1) | (xcd & 1);
}

// ---------------- K0: pack xyz -> recA.xyz + recB.xyz ----------------
__global__ __launch_bounds__(256) void k_pack(const float* __restrict__ xyz,
                                              float* __restrict__ ws){
  int p = blockIdx.x*256 + threadIdx.x;
  int b = p >> LOGN, n = p & (NPTS-1);
  const float* xb = xyz + b*3*NPTS + n;
  float4 v = make_float4(xb[0], xb[NPTS], xb[2*NPTS], 0.f);
  *(float4*)((char*)(ws + RECA_OFF) + (size_t)p*32 + 16) = v;
  *(float4*)((char*)(ws + RECB_OFF) + (size_t)p*32 + 16) = v;
}

// ---------------- fin: raw slots -> (scale,shift) per channel ----------------
__device__ void fin_stage(const float* __restrict__ ws, float* __restrict__ fin,
                          int stage, int nch, float cnt,
                          const float* __restrict__ gamma, const float* __restrict__ beta){
  int t = threadIdx.x;
  if(t >= 4*nch) return;
  int b = t / nch, c = t - b*nch;
  int g = c / (nch/4);
  const float* sl = ws + ((stage*4+b)*4+g)*128;
  float s=0.f, q=0.f;
  #pragma unroll 8
  for(int i=0;i<64;i++){ s += sl[i]; q += sl[64+i]; }
  float mean = s/cnt;
  float var  = q/cnt - mean*mean;
  float inv  = rsqrtf(var + EPSV);
  float sc = inv*gamma[c];
  float sh = beta[c] - mean*sc;
  float* fp = fin + ((stage*4+b)*32 + c)*2;
  fp[0]=sc; fp[1]=sh;
}

__global__ __launch_bounds__(128) void kfA(float* __restrict__ ws,
    const float* g1, const float* be1, const float* gL1, const float* beL1,
    const float* gsk, const float* besk){
  if(blockIdx.x==0)      fin_stage(ws, ws+FIN_OFF, ST_MLP1, 8,  2.0f*NPTS,      g1, be1);
  else if(blockIdx.x==1) fin_stage(ws, ws+FIN_OFF, ST_L1,   8,  2.0f*NPTS*KNB,  gL1, beL1);
  else                   fin_stage(ws, ws+FIN_OFF, ST_SKIP, 32, 8.0f*NPTS,      gsk, besk);
}
__global__ __launch_bounds__(128) void kfB(float* __restrict__ ws,
    const float* gm1, const float* bem1, const float* gL2, const float* beL2){
  if(blockIdx.x==0) fin_stage(ws, ws+FIN_OFF, ST_M1, 8, 2.0f*NPTS,     gm1, bem1);
  else              fin_stage(ws, ws+FIN_OFF, ST_L2, 8, 2.0f*NPTS*KNB, gL2, beL2);
}
__global__ __launch_bounds__(128) void kfC(float* __restrict__ ws,
    const float* gm2, const float* bem2){
  fin_stage(ws, ws+FIN_OFF, ST_M2, 16, 4.0f*NPTS, gm2, bem2);
}
__global__ __launch_bounds__(128) void kfD(float* __restrict__ ws,
    const float* go, const float* beo){
  fin_stage(ws, ws+FIN_OFF, ST_OUT, 32, 8.0f*NPTS, go, beo);
}

// ---------------- K1: mlp1 pre + stats; skip stats; lfa1 -> l1pre + stats ----------------
template<bool PAIR>
__global__ __launch_bounds__(256) void k1(
    const float* __restrict__ feat, const int* __restrict__ nidx,
    const float* __restrict__ W1,  const float* __restrict__ b1,
    const float* __restrict__ Ws,  const float* __restrict__ bs,
    const float* __restrict__ WL1, const float* __restrict__ bl1,
    float* __restrict__ ws){
  int b, nblk; xcd_map(blockIdx.x, b, nblk);
  int n = nblk*256 + threadIdx.x;
  int p = (b<<LOGN) | n;
  char* recA = (char*)(ws + RECA_OFF);
  char* pairb = (char*)(ws + PAIR_OFF);
  float f[8];
  #pragma unroll
  for(int c=0;c<8;c++) f[c] = __builtin_nontemporal_load(feat + (b*8+c)*NPTS + n);

  float s1s[4]={0,0,0,0}, s1q[4]={0,0,0,0};
  float pv[8];
  #pragma unroll
  for(int c=0;c<8;c++){
    float v = b1[c];
    #pragma unroll
    for(int j=0;j<8;j++) v += W1[c*8+j]*f[j];
    pv[c]=v;
    s1s[c>>1]+=v; s1q[c>>1]+=v*v;
  }
  uint4 pk = make_uint4(pkbf(pv[0],pv[1]), pkbf(pv[2],pv[3]),
                        pkbf(pv[4],pv[5]), pkbf(pv[6],pv[7]));
  *(uint4*)(recA + (size_t)p*32) = pk;

  float sss[4]={0,0,0,0}, ssq[4]={0,0,0,0};
  #pragma unroll
  for(int o=0;o<32;o++){
    float v = bs[o];
    #pragma unroll
    for(int j=0;j<8;j++) v += Ws[o*8+j]*f[j];
    sss[o>>3]+=v; ssq[o>>3]+=v*v;
  }
  float4 ct = *(const float4*)(recA + (size_t)p*32 + 16);
  float l1s[4]={0,0,0,0}, l1q[4]={0,0,0,0};
  const int* nr = nidx + p*KNB;
  #pragma unroll
  for(int k=0;k<KNB;k++){
    int idx = __builtin_nontemporal_load(nr + k);
    float4 nb = *(const float4*)(recA + ((size_t)((b<<LOGN)|idx))*32 + 16);
    float rx=nb.x-ct.x, ry=nb.y-ct.y, rz=nb.z-ct.z;
    float dd = __builtin_amdgcn_sqrtf(rx*rx+ry*ry+rz*rz);
    float fr[10] = {dd,rx,ry,rz,ct.x,ct.y,ct.z,nb.x,nb.y,nb.z};
    float lv[8];
    #pragma unroll
    for(int c=0;c<8;c++){
      float v = bl1[c];
      #pragma unroll
      for(int j=0;j<10;j++) v += WL1[c*10+j]*fr[j];
      lv[c]=v;
      l1s[c>>1]+=v; l1q[c>>1]+=v*v;
    }
    if constexpr (PAIR){
      u32x4 lp = { pkbf(lv[0],lv[1]), pkbf(lv[2],lv[3]),
                   pkbf(lv[4],lv[5]), pkbf(lv[6],lv[7]) };
      __builtin_nontemporal_store(lp, (u32x4*)(pairb + ((size_t)p*KNB + k)*16));
    }
  }
  __shared__ float lst[24];
  if(threadIdx.x < 24) lst[threadIdx.x] = 0.f;
  __syncthreads();
  int lane = threadIdx.x & 63;
  #pragma unroll
  for(int g=0; g<4; g++){
    float a1v = wred(s1s[g]), a2v = wred(s1q[g]);
    float d1v = wred(sss[g]), d2v = wred(ssq[g]);
    float e1v = wred(l1s[g]), e2v = wred(l1q[g]);
    if(lane==0){
      atomicAdd(&lst[ 0+g*2], a1v); atomicAdd(&lst[ 1+g*2], a2v);
      atomicAdd(&lst[ 8+g*2], d1v); atomicAdd(&lst[ 9+g*2], d2v);
      atomicAdd(&lst[16+g*2], e1v); atomicAdd(&lst[17+g*2], e2v);
    }
  }
  __syncthreads();
  if(threadIdx.x < 24){
    int stage = threadIdx.x >> 3;
    int g = (threadIdx.x >> 1) & 3;
    int w = threadIdx.x & 1;
    atomicAdd(ws + ((stage*4+b)*4+g)*128 + w*64 + (blockIdx.x&63), lst[threadIdx.x]);
  }
}

// ---------------- K2: att-pool 1 (MFMA S^T, permlane softmax, swizzled PV) ----------------
template<bool PAIR>
__global__ __launch_bounds__(256,8) void k2(
    const int* __restrict__ nidx,
    const float* __restrict__ WL1, const float* __restrict__ bl1,
    const float* __restrict__ Wa1,
    const float* __restrict__ Wm1, const float* __restrict__ bm1,
    const float* __restrict__ W2,  const float* __restrict__ b2,
    float* __restrict__ ws){
  const float* fin = ws + FIN_OFF;
  int b, nblk; xcd_map(blockIdx.x, b, nblk);
  int tid = threadIdx.x;
  int w = tid>>6, lane = tid&63, q = lane>>4, l15 = lane&15;
  int nbase = nblk*16 + w*4;
  int pA = (b<<LOGN) | (nbase + q);

  float scP[8], shP[8], scL[8], shL[8];
  #pragma unroll
  for(int c=0;c<8;c++){
    load_fin(fin, ST_MLP1,b,c, scP[c],shP[c]);
    load_fin(fin, ST_L1,  b,c, scL[c],shL[c]);
  }
  U16 bu; bu.u = make_uint4(0,0,0,0);
  if(q < 2){
    const float* wr = Wa1 + l15*16 + q*8;
    float4 w0 = *(const float4*)(wr);
    float4 w1 = *(const float4*)(wr+4);
    bu.u = make_uint4(pkbf(w0.x,w0.y), pkbf(w0.z,w0.w), pkbf(w1.x,w1.y), pkbf(w1.z,w1.w));
  }

  __shared__ unsigned char SB[4][WV_BYTES];
  __shared__ float lst[16];
  if(tid<16) lst[tid]=0.f;
  char* wb = (char*)SB[w];

  char* recA = (char*)(ws + RECA_OFF);
  char* recB = (char*)(ws + RECB_OFF);
  char* pairb = (char*)(ws + PAIR_OFF);

  // ---- phase A: lane = (point q, neighbor l15) ----
  int idx = __builtin_nontemporal_load(nidx + (size_t)pA*KNB + l15);
  const char* rp = recA + ((size_t)((b<<LOGN)|idx))*32;
  uint4 pk1  = *(const uint4*)(rp);
  float fx[8];
  if constexpr (PAIR){
    u32x4 lp = __builtin_nontemporal_load(
        (const u32x4*)(pairb + ((size_t)pA*KNB + l15)*16));
    fx[0]=lrelu(blo(lp.x)*scL[0]+shL[0]); fx[1]=lrelu(bhi(lp.x)*scL[1]+shL[1]);
    fx[2]=lrelu(blo(lp.y)*scL[2]+shL[2]); fx[3]=lrelu(bhi(lp.y)*scL[3]+shL[3]);
    fx[4]=lrelu(blo(lp.z)*scL[4]+shL[4]); fx[5]=lrelu(bhi(lp.z)*scL[5]+shL[5]);
    fx[6]=lrelu(blo(lp.w)*scL[6]+shL[6]); fx[7]=lrelu(bhi(lp.w)*scL[7]+shL[7]);
  } else {
    float4 nb  = *(const float4*)(rp + 16);
    float4 ct  = *(const float4*)(recA + (size_t)pA*32 + 16);
    float rx=nb.x-ct.x, ry=nb.y-ct.y, rz=nb.z-ct.z;
    float dd = __builtin_amdgcn_sqrtf(rx*rx+ry*ry+rz*rz);
    float fr[10] = {dd,rx,ry,rz,ct.x,ct.y,ct.z,nb.x,nb.y,nb.z};
    #pragma unroll
    for(int c=0;c<8;c++){
      float v = bl1[c];
      #pragma unroll
      for(int j=0;j<10;j++) v += WL1[c*10+j]*fr[j];
      fx[c] = lrelu(v*scL[c]+shL[c]);
    }
  }
  float xn[8];
  xn[0]=lrelu(blo(pk1.x)*scP[0]+shP[0]); xn[1]=lrelu(bhi(pk1.x)*scP[1]+shP[1]);
  xn[2]=lrelu(blo(pk1.y)*scP[2]+shP[2]); xn[3]=lrelu(bhi(pk1.y)*scP[3]+shP[3]);
  xn[4]=lrelu(blo(pk1.z)*scP[4]+shP[4]); xn[5]=lrelu(bhi(pk1.z)*scP[5]+shP[5]);
  xn[6]=lrelu(blo(pk1.w)*scP[6]+shP[6]); xn[7]=lrelu(bhi(pk1.w)*scP[7]+shP[7]);

  {
    uint4 d0 = make_uint4(pkbf(xn[0],xn[1]), pkbf(xn[2],xn[3]), pkbf(xn[4],xn[5]), pkbf(xn[6],xn[7]));
    uint4 d1 = make_uint4(pkbf(fx[0],fx[1]), pkbf(fx[2],fx[3]), pkbf(fx[4],fx[5]), pkbf(fx[6],fx[7]));
    char* base = wb + XB_OFF + q*256 + rowadr(l15);
    *(uint4*)(base)        = d0;
    *(uint4*)(base + 1024) = d1;
  }

  // lfa2 pre-GN values (store into SAME pair slot -> becomes l2pre for k3)
  float l2v[8];
  #pragma unroll
  for(int c=0;c<8;c++){
    float v = b2[c];
    #pragma unroll
    for(int j=0;j<8;j++) v += W2[c*8+j]*fx[j];
    l2v[c]=v;
  }
  if constexpr (PAIR){
    u32x4 lp2 = { pkbf(l2v[0],l2v[1]), pkbf(l2v[2],l2v[3]),
                  pkbf(l2v[4],l2v[5]), pkbf(l2v[6],l2v[7]) };
    __builtin_nontemporal_store(lp2, (u32x4*)(pairb + ((size_t)pA*KNB + l15)*16));
  }

  wave_fence();

  // ---- phase B: per point pt: MFMA S^T + permlane softmax + swizzled PV ----
  f32x4 cz = {0.f,0.f,0.f,0.f};
  int rxf = q & 2;
  const char* xc = wb + XB_OFF + (l15>>3)*1024 + (l15&7)*2;
  #pragma unroll
  for(int pt=0; pt<4; pt++){
    U16 afr; afr.u = make_uint4(0,0,0,0);
    if(q < 2) afr.u = *(const uint4*)(wb + XB_OFF + q*1024 + pt*256 + rowadr(l15));
    f32x4 cf = __builtin_amdgcn_mfma_f32_16x16x32_bf16(afr.s, bu.s, cz, 0,0,0);
    float mx = fmaxf(fmaxf(cf[0],cf[1]), fmaxf(cf[2],cf[3]));
    mx = x16max(mx); mx = x32max(mx);
    float pe0=__expf(cf[0]-mx), pe1=__expf(cf[1]-mx), pe2=__expf(cf[2]-mx), pe3=__expf(cf[3]-mx);
    float ps = pe0+pe1+pe2+pe3;
    ps = s16(ps); ps = s32(ps);
    const char* xe = xc + pt*256 + 64*q;
    float acc = pe0*bfu(*(const unsigned short*)(xe + 16*(0^rxf)))
              + pe1*bfu(*(const unsigned short*)(xe + 16*(1^rxf)))
              + pe2*bfu(*(const unsigned short*)(xe + 16*(2^rxf)))
              + pe3*bfu(*(const unsigned short*)(xe + 16*(3^rxf)));
    acc = s16(acc); acc = s32(acc);
    float agg = acc*__builtin_amdgcn_rcpf(ps);
    if(q==0) *(float*)(wb + AG_OFF + (pt*16+l15)*4) = agg;
  }

  // lfa2 stats
  float l2s[4]={0,0,0,0}, l2q[4]={0,0,0,0};
  #pragma unroll
  for(int c=0;c<8;c++){ l2s[c>>1]+=l2v[c]; l2q[c>>1]+=l2v[c]*l2v[c]; }

  wave_fence();

  // ---- phase D: point = q, out channel o = l15 (<8) ----
  float m1v = 0.f;
  if(l15 < 8){
    const float4* agp = (const float4*)(wb + AG_OFF + q*64);
    float4 A0=agp[0], A1=agp[1], A2=agp[2], A3=agp[3];
    const float4* wp = (const float4*)(Wm1 + l15*16);
    float4 W0=wp[0], W1_=wp[1], W2_=wp[2], W3=wp[3];
    float v = bm1[l15];
    v += W0.x*A0.x + W0.y*A0.y + W0.z*A0.z + W0.w*A0.w;
    v += W1_.x*A1.x + W1_.y*A1.y + W1_.z*A1.z + W1_.w*A1.w;
    v += W2_.x*A2.x + W2_.y*A2.y + W2_.z*A2.z + W2_.w*A2.w;
    v += W3.x*A3.x + W3.y*A3.y + W3.z*A3.z + W3.w*A3.w;
    m1v = v;
  }
  float vpart = __shfl_xor(m1v, 1);
  if(l15 < 8 && (l15&1)==0){
    unsigned u = pkbf(m1v, vpart);
    int pD = (b<<LOGN) | (nbase + q);
    *(unsigned*)(recB + (size_t)pD*32 + (l15>>1)*4) = u;
  }
  float m1s = s16(m1v); m1s = s32(m1s); m1s += __shfl_xor(m1s,1);
  float m1qv = m1v*m1v;
  float m1q = s16(m1qv); m1q = s32(m1q); m1q += __shfl_xor(m1q,1);

  __syncthreads();
  #pragma unroll
  for(int g=0;g<4;g++){
    float a=wred(l2s[g]), qq=wred(l2q[g]);
    if(lane==0){ atomicAdd(&lst[g*2],a); atomicAdd(&lst[g*2+1],qq); }
  }
  if(lane < 8 && (lane&1)==0){
    atomicAdd(&lst[8+(lane>>1)*2],   m1s);
    atomicAdd(&lst[8+(lane>>1)*2+1], m1q);
  }
  __syncthreads();
  if(tid<16){
    int half=tid>>3, g=(tid>>1)&3, wsel=tid&1;
    int stage = half? ST_M1 : ST_L2;
    atomicAdd(ws + ((stage*4+b)*4+g)*128 + wsel*64 + (blockIdx.x&63), lst[tid]);
  }
}

// ---------------- K3: att-pool 2 (MFMA S^T, permlane softmax, swizzled PV) ----------------
template<bool PAIR>
__global__ __launch_bounds__(256,8) void k3(
    const int* __restrict__ nidx,
    const float* __restrict__ WL1, const float* __restrict__ bl1,
    const float* __restrict__ W2,  const float* __restrict__ b2,
    const float* __restrict__ Wa2,
    const float* __restrict__ Wm2, const float* __restrict__ bm2,
    float* __restrict__ ws){
  const float* fin = ws + FIN_OFF;
  int b, nblk; xcd_map(blockIdx.x, b, nblk);
  int tid = threadIdx.x;
  int w = tid>>6, lane = tid&63, q = lane>>4, l15 = lane&15;
  int nbase = nblk*16 + w*4;
  int pA = (b<<LOGN) | (nbase + q);

  float scL[8], shL[8], scL2[8], shL2[8], scM[8], shM[8];
  #pragma unroll
  for(int c=0;c<8;c++){
    load_fin(fin, ST_L1, b,c, scL[c], shL[c]);
    load_fin(fin, ST_L2, b,c, scL2[c],shL2[c]);
    load_fin(fin, ST_M1, b,c, scM[c], shM[c]);
  }
  U16 bu; bu.u = make_uint4(0,0,0,0);
  if(q < 2){
    const float* wr = Wa2 + l15*16 + q*8;
    float4 w0 = *(const float4*)(wr);
    float4 w1 = *(const float4*)(wr+4);
    bu.u = make_uint4(pkbf(w0.x,w0.y), pkbf(w0.z,w0.w), pkbf(w1.x,w1.y), pkbf(w1.z,w1.w));
  }
  float wmr[16];
  {
    const float4* wp = (const float4*)(Wm2 + l15*16);
    float4 m0=wp[0], m1=wp[1], m2=wp[2], m3=wp[3];
    wmr[0]=m0.x; wmr[1]=m0.y; wmr[2]=m0.z; wmr[3]=m0.w;
    wmr[4]=m1.x; wmr[5]=m1.y; wmr[6]=m1.z; wmr[7]=m1.w;
    wmr[8]=m2.x; wmr[9]=m2.y; wmr[10]=m2.z; wmr[11]=m2.w;
    wmr[12]=m3.x; wmr[13]=m3.y; wmr[14]=m3.z; wmr[15]=m3.w;
  }

  __shared__ unsigned char SB[4][WV_BYTES];
  __shared__ float lst[8];
  if(tid<8) lst[tid]=0.f;
  char* wb = (char*)SB[w];

  char* recB = (char*)(ws + RECB_OFF);
  char* pairb = (char*)(ws + PAIR_OFF);
  float* prem2 = ws + PREM2_OFF;

  // ---- phase A ----
  int idx = __builtin_nontemporal_load(nidx + (size_t)pA*KNB + l15);
  const char* rp = recB + ((size_t)((b<<LOGN)|idx))*32;
  uint4 pm1 = *(const uint4*)(rp);
  float fx2[8];
  if constexpr (PAIR){
    u32x4 lp = __builtin_nontemporal_load(
        (const u32x4*)(pairb + ((size_t)pA*KNB + l15)*16));
    fx2[0]=lrelu(blo(lp.x)*scL2[0]+shL2[0]); fx2[1]=lrelu(bhi(lp.x)*scL2[1]+shL2[1]);
    fx2[2]=lrelu(blo(lp.y)*scL2[2]+shL2[2]); fx2[3]=lrelu(bhi(lp.y)*scL2[3]+shL2[3]);
    fx2[4]=lrelu(blo(lp.z)*scL2[4]+shL2[4]); fx2[5]=lrelu(bhi(lp.z)*scL2[5]+shL2[5]);
    fx2[6]=lrelu(blo(lp.w)*scL2[6]+shL2[6]); fx2[7]=lrelu(bhi(lp.w)*scL2[7]+shL2[7]);
  } else {
    float4 nb = *(const float4*)(rp + 16);
    float4 ct = *(const float4*)(recB + (size_t)pA*32 + 16);
    float rx=nb.x-ct.x, ry=nb.y-ct.y, rz=nb.z-ct.z;
    float dd = __builtin_amdgcn_sqrtf(rx*rx+ry*ry+rz*rz);
    float fr[10] = {dd,rx,ry,rz,ct.x,ct.y,ct.z,nb.x,nb.y,nb.z};
    float fx[8];
    #pragma unroll
    for(int c=0;c<8;c++){
      float v = bl1[c];
      #pragma unroll
      for(int j=0;j<10;j++) v += WL1[c*10+j]*fr[j];
      fx[c] = lrelu(v*scL[c]+shL[c]);
    }
    #pragma unroll
    for(int c=0;c<8;c++){
      float v = b2[c];
      #pragma unroll
      for(int j=0;j<8;j++) v += W2[c*8+j]*fx[j];
      fx2[c] = lrelu(v*scL2[c]+shL2[c]);
    }
  }
  float xn[8];
  xn[0]=lrelu(blo(pm1.x)*scM[0]+shM[0]); xn[1]=lrelu(bhi(pm1.x)*scM[1]+shM[1]);
  xn[2]=lrelu(blo(pm1.y)*scM[2]+shM[2]); xn[3]=lrelu(bhi(pm1.y)*scM[3]+shM[3]);
  xn[4]=lrelu(blo(pm1.z)*scM[4]+shM[4]); xn[5]=lrelu(bhi(pm1.z)*scM[5]+shM[5]);
  xn[6]=lrelu(blo(pm1.w)*scM[6]+shM[6]); xn[7]=lrelu(bhi(pm1.w)*scM[7]+shM[7]);

  {
    uint4 d0 = make_uint4(pkbf(xn[0],xn[1]), pkbf(xn[2],xn[3]), pkbf(xn[4],xn[5]), pkbf(xn[6],xn[7]));
    uint4 d1 = make_uint4(pkbf(fx2[0],fx2[1]), pkbf(fx2[2],fx2[3]), pkbf(fx2[4],fx2[5]), pkbf(fx2[6],fx2[7]));
    char* base = wb + XB_OFF + q*256 + rowadr(l15);
    *(uint4*)(base)        = d0;
    *(uint4*)(base + 1024) = d1;
  }

  wave_fence();

  f32x4 cz = {0.f,0.f,0.f,0.f};
  int rxf = q & 2;
  const char* xc = wb + XB_OFF + (l15>>3)*1024 + (l15&7)*2;
  #pragma unroll
  for(int pt=0; pt<4; pt++){
    U16 afr; afr.u = make_uint4(0,0,0,0);
    if(q < 2) afr.u = *(const uint4*)(wb + XB_OFF + q*1024 + pt*256 + rowadr(l15));
    f32x4 cf = __builtin_amdgcn_mfma_f32_16x16x32_bf16(afr.s, bu.s, cz, 0,0,0);
    float mx = fmaxf(fmaxf(cf[0],cf[1]), fmaxf(cf[2],cf[3]));
    mx = x16max(mx); mx = x32max(mx);
    float pe0=__expf(cf[0]-mx), pe1=__expf(cf[1]-mx), pe2=__expf(cf[2]-mx), pe3=__expf(cf[3]-mx);
    float ps = pe0+pe1+pe2+pe3;
    ps = s16(ps); ps = s32(ps);
    const char* xe = xc + pt*256 + 64*q;
    float acc = pe0*bfu(*(const unsigned short*)(xe + 16*(0^rxf)))
              + pe1*bfu(*(const unsigned short*)(xe + 16*(1^rxf)))
              + pe2*bfu(*(const unsigned short*)(xe + 16*(2^rxf)))
              + pe3*bfu(*(const unsigned short*)(xe + 16*(3^rxf)));
    acc = s16(acc); acc = s32(acc);
    float agg = acc*__builtin_amdgcn_rcpf(ps);
    if(q==0) *(float*)(wb + AG_OFF + (pt*16+l15)*4) = agg;
  }

  wave_fence();

  // ---- phase D: point = q, out channel o = l15 ----
  float v;
  {
    const float4* agp = (const float4*)(wb + AG_OFF + q*64);
    float4 A0=agp[0], A1=agp[1], A2=agp[2], A3=agp[3];
    v = bm2[l15];
    v += wmr[0]*A0.x + wmr[1]*A0.y + wmr[2]*A0.z + wmr[3]*A0.w;
    v += wmr[4]*A1.x + wmr[5]*A1.y + wmr[6]*A1.z + wmr[7]*A1.w;
    v += wmr[8]*A2.x + wmr[9]*A2.y + wmr[10]*A2.z + wmr[11]*A2.w;
    v += wmr[12]*A3.x + wmr[13]*A3.y + wmr[14]*A3.z + wmr[15]*A3.w;
  }
  int pD = (b<<LOGN) | (nbase + q);
  __builtin_nontemporal_store(v, prem2 + (size_t)pD*16 + l15);

  float s = s16(v);  s = s32(s);  s += __shfl_xor(s,1);  s += __shfl_xor(s,2);
  float qv = v*v;
  float qq = s16(qv); qq = s32(qq); qq += __shfl_xor(qq,1); qq += __shfl_xor(qq,2);

  __syncthreads();
  if(lane < 16 && (lane&3)==0){
    atomicAdd(&lst[(lane>>2)*2],   s);
    atomicAdd(&lst[(lane>>2)*2+1], qq);
  }
  __syncthreads();
  if(tid<8){
    int g=(tid>>1)&3, wsel=tid&1;
    atomicAdd(ws + ((ST_M2*4+b)*4+g)*128 + wsel*64 + (blockIdx.x&63), lst[tid]);
  }
}

// ---------------- K4: stats of mlp2 output ----------------
__global__ __launch_bounds__(256) void k4(
    const float* __restrict__ Wo,  const float* __restrict__ bo,
    float* __restrict__ ws){
  const float* fin = ws + FIN_OFF;
  int b=blockIdx.y; int n=blockIdx.x*256+threadIdx.x; int p=(b<<LOGN)|n;
  float scM[16], shM[16];
  #pragma unroll
  for(int c=0;c<16;c++) load_fin(fin, ST_M2, b, c, scM[c], shM[c]);
  const f32x4* pm = (const f32x4*)(ws + PREM2_OFF) + (size_t)p*4;
  float fa[16];
  #pragma unroll
  for(int i=0;i<4;i++){
    f32x4 v4 = __builtin_nontemporal_load(pm + i);
    fa[i*4+0]=lrelu(v4.x*scM[i*4+0]+shM[i*4+0]);
    fa[i*4+1]=lrelu(v4.y*scM[i*4+1]+shM[i*4+1]);
    fa[i*4+2]=lrelu(v4.z*scM[i*4+2]+shM[i*4+2]);
    fa[i*4+3]=lrelu(v4.w*scM[i*4+3]+shM[i*4+3]);
  }
  float sos[4]={0,0,0,0}, soq[4]={0,0,0,0};
  #pragma unroll
  for(int o=0;o<32;o++){
    float v=bo[o];
    #pragma unroll
    for(int c=0;c<16;c++) v += Wo[o*16+c]*fa[c];
    sos[o>>3]+=v; soq[o>>3]+=v*v;
  }
  __shared__ float lst[8];
  if(threadIdx.x<8) lst[threadIdx.x]=0.f;
  __syncthreads();
  int lane = threadIdx.x & 63;
  #pragma unroll
  for(int g=0;g<4;g++){
    float a=wred(sos[g]), q=wred(soq[g]);
    if(lane==0){ atomicAdd(&lst[g*2],a); atomicAdd(&lst[g*2+1],q); }
  }
  __syncthreads();
  if(threadIdx.x<8){
    int g=(threadIdx.x>>1)&3, w=threadIdx.x&1;
    atomicAdd(ws + ((ST_OUT*4+b)*4+g)*128 + w*64 + (blockIdx.x&63), lst[threadIdx.x]);
  }
}

// ---------------- K5: final out ----------------
__global__ __launch_bounds__(256) void k5(
    const float* __restrict__ feat,
    const float* __restrict__ Wo,  const float* __restrict__ bo,
    const float* __restrict__ Wsk, const float* __restrict__ bsk,
    const float* __restrict__ ws, float* __restrict__ out){
  const float* fin = ws + FIN_OFF;
  int b=blockIdx.y; int n=blockIdx.x*256+threadIdx.x; int p=(b<<LOGN)|n;
  float scM[16], shM[16];
  #pragma unroll
  for(int c=0;c<16;c++) load_fin(fin, ST_M2, b, c, scM[c], shM[c]);
  const f32x4* pm = (const f32x4*)(ws + PREM2_OFF) + (size_t)p*4;
  float fa[16];
  #pragma unroll
  for(int i=0;i<4;i++){
    f32x4 v4 = __builtin_nontemporal_load(pm + i);
    fa[i*4+0]=lrelu(v4.x*scM[i*4+0]+shM[i*4+0]);
    fa[i*4+1]=lrelu(v4.y*scM[i*4+1]+shM[i*4+1]);
    fa[i*4+2]=lrelu(v4.z*scM[i*4+2]+shM[i*4+2]);
    fa[i*4+3]=lrelu(v4.w*scM[i*4+3]+shM[i*4+3]);
  }
  float f[8];
  #pragma unroll
  for(int c=0;c<8;c++) f[c]=__builtin_nontemporal_load(feat + (b*8+c)*NPTS + n);
  #pragma unroll
  for(int o=0;o<32;o++){
    float to = bo[o];
    #pragma unroll
    for(int c=0;c<16;c++) to += Wo[o*16+c]*fa[c];
    float ts = bsk[o];
    #pragma unroll
    for(int j=0;j<8;j++) ts += Wsk[o*8+j]*f[j];
    float scO, shO, scS, shS;
    load_fin(fin, ST_OUT,  b, o, scO, shO);
    load_fin(fin, ST_SKIP, b, o, scS, shS);
    float v = to*scO+shO + ts*scS+shS;
    __builtin_nontemporal_store(lrelu(v), out + (size_t)(b*32+o)*NPTS + n);
  }
}

extern "C" void kernel_launch(void* const* d_in, const int* in_sizes, int n_in,
                              void* d_out, int out_size, void* d_ws, size_t ws_size,
                              hipStream_t stream){
  (void)in_sizes; (void)n_in; (void)out_size;
  const float* feat=(const float*)d_in[0];
  const float* xyz =(const float*)d_in[1];
  const int*   nidx=(const int*)d_in[2];
  const float* W1  =(const float*)d_in[3];
  const float* b1  =(const float*)d_in[4];
  const float* g1  =(const float*)d_in[5];
  const float* be1 =(const float*)d_in[6];
  const float* WL1 =(const float*)d_in[7];
  const float* bl1 =(const float*)d_in[8];
  const float* gL1 =(const float*)d_in[9];
  const float* beL1=(const float*)d_in[10];
  const float* Wa1 =(const float*)d_in[11];
  const float* Wm1 =(const float*)d_in[12];
  const float* bm1 =(const float*)d_in[13];
  const float* gm1 =(const float*)d_in[14];
  const float* bem1=(const float*)d_in[15];
  const float* W2  =(const float*)d_in[16];
  const float* b2  =(const float*)d_in[17];
  const float* gL2 =(const float*)d_in[18];
  const float* beL2=(const float*)d_in[19];
  const float* Wa2 =(const float*)d_in[20];
  const float* Wm2 =(const float*)d_in[21];
  const float* bm2 =(const float*)d_in[22];
  const float* gm2 =(const float*)d_in[23];
  const float* bem2=(const float*)d_in[24];
  const float* Wo  =(const float*)d_in[25];
  const float* bo  =(const float*)d_in[26];
  const float* go  =(const float*)d_in[27];
  const float* beo =(const float*)d_in[28];
  const float* Wsk =(const float*)d_in[29];
  const float* bsk =(const float*)d_in[30];
  const float* gsk =(const float*)d_in[31];
  const float* besk=(const float*)d_in[32];
  float* ws=(float*)d_ws;
  float* out=(float*)d_out;

  bool usePair = (ws_size >= NEED_BYTES);

  hipMemsetAsync(d_ws, 0, STAT_F*sizeof(float), stream);
  k_pack<<<dim3(1024),dim3(256),0,stream>>>(xyz, ws);
  if(usePair)
    k1<true><<<dim3(1024),dim3(256),0,stream>>>(feat, nidx, W1,b1, Wsk,bsk, WL1,bl1, ws);
  else
    k1<false><<<dim3(1024),dim3(256),0,stream>>>(feat, nidx, W1,b1, Wsk,bsk, WL1,bl1, ws);
  kfA<<<dim3(3),dim3(128),0,stream>>>(ws, g1,be1, gL1,beL1, gsk,besk);
  if(usePair)
    k2<true><<<dim3(16384),dim3(256),0,stream>>>(nidx, WL1,bl1, Wa1, Wm1,bm1, W2,b2, ws);
  else
    k2<false><<<dim3(16384),dim3(256),0,stream>>>(nidx, WL1,bl1, Wa1, Wm1,bm1, W2,b2, ws);
  kfB<<<dim3(2),dim3(128),0,stream>>>(ws, gm1,bem1, gL2,beL2);
  if(usePair)
    k3<true><<<dim3(16384),dim3(256),0,stream>>>(nidx, WL1,bl1, W2,b2, Wa2, Wm2,bm2, ws);
  else
    k3<false><<<dim3(16384),dim3(256),0,stream>>>(nidx, WL1,bl1, W2,b2, Wa2, Wm2,bm2, ws);
  kfC<<<dim3(1),dim3(128),0,stream>>>(ws, gm2,bem2);
  k4<<<dim3(256,4),dim3(256),0,stream>>>(Wo,bo, ws);
  kfD<<<dim3(1),dim3(128),0,stream>>>(ws, go,beo);
  k5<<<dim3(256,4),dim3(256),0,stream>>>(feat, Wo,bo, Wsk,bsk, ws, out);
}

// Round 14
// 269.465 us; speedup vs baseline: 1.4692x; 1.4692x over previous
//
#include <hip/hip_runtime.h>
#include <hip/hip_bf16.h>

#define NPTS 65536
#define LOGN 16
#define KNB 16
#define NEGS 0.2f
#define EPSV 1e-5f

// GN stages
#define ST_MLP1 0
#define ST_SKIP 1
#define ST_L1   2
#define ST_M1   3
#define ST_L2   4
#define ST_M2   5
#define ST_OUT  6

// ws layout (floats): raw stats | fin | recA (32B/pt) | recB (32B/pt) | prem2 | pairbuf
// recA: [pre1 bf16x8 (16B)][xyz f32x3 (12B)][pad]   -- gathered by k1,k2
// recB: [prem1 bf16x8 (16B)][xyz f32x3 (12B)][pad]  -- gathered by k3
// pairbuf: bf16x8 per (point,neighbor) pair: k2 writes l2pre (lane=pair, coalesced),
//          k3 reads l2pre. NO writes to pairbuf from point-parallel kernels (R13 lesson).
#define STAT_F   14336                       // 7*4*4*128
#define FIN_OFF  14336
#define RECA_OFF 16384
#define RECB_OFF  (RECA_OFF + 4*NPTS*8)
#define PREM2_OFF (RECB_OFF + 4*NPTS*8)
#define PAIR_OFF  (PREM2_OFF + 4*NPTS*16)
#define PAIR_FLOATS ((size_t)4*NPTS*KNB*4)
#define NEED_BYTES (((size_t)PAIR_OFF + PAIR_FLOATS)*4)

typedef __attribute__((ext_vector_type(8))) short short8;
typedef __attribute__((ext_vector_type(4))) float f32x4;
typedef __attribute__((ext_vector_type(4))) unsigned u32x4;

union U16 { uint4 u; short8 s; };

__device__ __forceinline__ float lrelu(float v){ return fmaxf(v, v*NEGS); }

#if defined(__has_builtin)
#  if __has_builtin(__builtin_amdgcn_permlane32_swap)
#    define HAVE_PL32 1
#  endif
#  if __has_builtin(__builtin_amdgcn_permlane16_swap)
#    define HAVE_PL16 1
#  endif
#endif

// cross-lane over lane^16 / lane^32: VALU permlane swaps (no LDS pipe).
__device__ __forceinline__ float s16(float v){
#ifdef HAVE_PL16
  unsigned u = __builtin_bit_cast(unsigned, v);
  auto r = __builtin_amdgcn_permlane16_swap(u, u, false, false);
  return __builtin_bit_cast(float,(unsigned)r[0]) + __builtin_bit_cast(float,(unsigned)r[1]);
#else
  return v + __shfl_xor(v,16);
#endif
}
__device__ __forceinline__ float s32(float v){
#ifdef HAVE_PL32
  unsigned u = __builtin_bit_cast(unsigned, v);
  auto r = __builtin_amdgcn_permlane32_swap(u, u, false, false);
  return __builtin_bit_cast(float,(unsigned)r[0]) + __builtin_bit_cast(float,(unsigned)r[1]);
#else
  return v + __shfl_xor(v,32);
#endif
}
__device__ __forceinline__ float x16max(float v){
#ifdef HAVE_PL16
  unsigned u = __builtin_bit_cast(unsigned, v);
  auto r = __builtin_amdgcn_permlane16_swap(u, u, false, false);
  return fmaxf(__builtin_bit_cast(float,(unsigned)r[0]), __builtin_bit_cast(float,(unsigned)r[1]));
#else
  return fmaxf(v, __shfl_xor(v,16));
#endif
}
__device__ __forceinline__ float x32max(float v){
#ifdef HAVE_PL32
  unsigned u = __builtin_bit_cast(unsigned, v);
  auto r = __builtin_amdgcn_permlane32_swap(u, u, false, false);
  return fmaxf(__builtin_bit_cast(float,(unsigned)r[0]), __builtin_bit_cast(float,(unsigned)r[1]));
#else
  return fmaxf(v, __shfl_xor(v,32));
#endif
}

__device__ __forceinline__ float wred(float v){
  v += __shfl_xor(v,1); v += __shfl_xor(v,2); v += __shfl_xor(v,4); v += __shfl_xor(v,8);
  v = s16(v); return s32(v);
}

__device__ __forceinline__ void wave_fence(){
  __builtin_amdgcn_sched_barrier(0);
  asm volatile("s_waitcnt lgkmcnt(0)" ::: "memory");
  __builtin_amdgcn_sched_barrier(0);
}

__device__ __forceinline__ void load_fin(const float* fin, int stage, int b, int c,
                                         float& sc, float& sh){
  const float* fp = fin + ((stage*4+b)*32 + c)*2;
  sc = fp[0]; sh = fp[1];
}

__device__ __forceinline__ unsigned pkbf(float a, float b){
  __hip_bfloat162 h = __float22bfloat162_rn(make_float2(a,b));
  union{ __hip_bfloat162 h2; unsigned u; } cv; cv.h2 = h; return cv.u;
}
__device__ __forceinline__ float blo(unsigned d){ return __builtin_bit_cast(float, d<<16); }
__device__ __forceinline__ float bhi(unsigned d){ return __builtin_bit_cast(float, d & 0xffff0000u); }
__device__ __forceinline__ float bfu(unsigned short h){ return __builtin_bit_cast(float, ((unsigned)h)<<16); }

// XB row address swizzle: rows 8-15 get bit5 flipped -> PV q-groups hit disjoint banks
__device__ __forceinline__ int rowadr(int row){ return (row*16) ^ ((row&8)<<2); }

// per-wave LDS region: XB planes (2 x 1024B) + AG (256B)
#define XB_OFF 0
#define AG_OFF 2048
#define WV_BYTES 2304

// batch<->XCD affinity decode: bid%8 = XCD (round-robin dispatch heuristic)
__device__ __forceinline__ void xcd_map(int bid, int& b, int& nblk){
  int xcd = bid & 7;
  b = xcd >> 1;
  nblk = ((bid >> 3) << 1) | (xcd & 1);
}

// ---------------- K0: pack xyz -> recA.xyz + recB.xyz ----------------
__global__ __launch_bounds__(256) void k_pack(const float* __restrict__ xyz,
                                              float* __restrict__ ws){
  int p = blockIdx.x*256 + threadIdx.x;
  int b = p >> LOGN, n = p & (NPTS-1);
  const float* xb = xyz + b*3*NPTS + n;
  float4 v = make_float4(xb[0], xb[NPTS], xb[2*NPTS], 0.f);
  *(float4*)((char*)(ws + RECA_OFF) + (size_t)p*32 + 16) = v;
  *(float4*)((char*)(ws + RECB_OFF) + (size_t)p*32 + 16) = v;
}

// ---------------- fin: raw slots -> (scale,shift) per channel ----------------
__device__ void fin_stage(const float* __restrict__ ws, float* __restrict__ fin,
                          int stage, int nch, float cnt,
                          const float* __restrict__ gamma, const float* __restrict__ beta){
  int t = threadIdx.x;
  if(t >= 4*nch) return;
  int b = t / nch, c = t - b*nch;
  int g = c / (nch/4);
  const float* sl = ws + ((stage*4+b)*4+g)*128;
  float s=0.f, q=0.f;
  #pragma unroll 8
  for(int i=0;i<64;i++){ s += sl[i]; q += sl[64+i]; }
  float mean = s/cnt;
  float var  = q/cnt - mean*mean;
  float inv  = rsqrtf(var + EPSV);
  float sc = inv*gamma[c];
  float sh = beta[c] - mean*sc;
  float* fp = fin + ((stage*4+b)*32 + c)*2;
  fp[0]=sc; fp[1]=sh;
}

__global__ __launch_bounds__(128) void kfA(float* __restrict__ ws,
    const float* g1, const float* be1, const float* gL1, const float* beL1,
    const float* gsk, const float* besk){
  if(blockIdx.x==0)      fin_stage(ws, ws+FIN_OFF, ST_MLP1, 8,  2.0f*NPTS,      g1, be1);
  else if(blockIdx.x==1) fin_stage(ws, ws+FIN_OFF, ST_L1,   8,  2.0f*NPTS*KNB,  gL1, beL1);
  else                   fin_stage(ws, ws+FIN_OFF, ST_SKIP, 32, 8.0f*NPTS,      gsk, besk);
}
__global__ __launch_bounds__(128) void kfB(float* __restrict__ ws,
    const float* gm1, const float* bem1, const float* gL2, const float* beL2){
  if(blockIdx.x==0) fin_stage(ws, ws+FIN_OFF, ST_M1, 8, 2.0f*NPTS,     gm1, bem1);
  else              fin_stage(ws, ws+FIN_OFF, ST_L2, 8, 2.0f*NPTS*KNB, gL2, beL2);
}
__global__ __launch_bounds__(128) void kfC(float* __restrict__ ws,
    const float* gm2, const float* bem2){
  fin_stage(ws, ws+FIN_OFF, ST_M2, 16, 4.0f*NPTS, gm2, bem2);
}
__global__ __launch_bounds__(128) void kfD(float* __restrict__ ws,
    const float* go, const float* beo){
  fin_stage(ws, ws+FIN_OFF, ST_OUT, 32, 8.0f*NPTS, go, beo);
}

// ---------------- K1: mlp1 pre(bf16 in recA) + stats; skip stats; lfa1 stats ----------------
__global__ __launch_bounds__(256) void k1(
    const float* __restrict__ feat, const int* __restrict__ nidx,
    const float* __restrict__ W1,  const float* __restrict__ b1,
    const float* __restrict__ Ws,  const float* __restrict__ bs,
    const float* __restrict__ WL1, const float* __restrict__ bl1,
    float* __restrict__ ws){
  int b, nblk; xcd_map(blockIdx.x, b, nblk);
  int n = nblk*256 + threadIdx.x;
  int p = (b<<LOGN) | n;
  char* recA = (char*)(ws + RECA_OFF);
  float f[8];
  #pragma unroll
  for(int c=0;c<8;c++) f[c] = __builtin_nontemporal_load(feat + (b*8+c)*NPTS + n);

  float s1s[4]={0,0,0,0}, s1q[4]={0,0,0,0};
  float pv[8];
  #pragma unroll
  for(int c=0;c<8;c++){
    float v = b1[c];
    #pragma unroll
    for(int j=0;j<8;j++) v += W1[c*8+j]*f[j];
    pv[c]=v;
    s1s[c>>1]+=v; s1q[c>>1]+=v*v;
  }
  uint4 pk = make_uint4(pkbf(pv[0],pv[1]), pkbf(pv[2],pv[3]),
                        pkbf(pv[4],pv[5]), pkbf(pv[6],pv[7]));
  *(uint4*)(recA + (size_t)p*32) = pk;

  float sss[4]={0,0,0,0}, ssq[4]={0,0,0,0};
  #pragma unroll
  for(int o=0;o<32;o++){
    float v = bs[o];
    #pragma unroll
    for(int j=0;j<8;j++) v += Ws[o*8+j]*f[j];
    sss[o>>3]+=v; ssq[o>>3]+=v*v;
  }
  float4 ct = *(const float4*)(recA + (size_t)p*32 + 16);
  float l1s[4]={0,0,0,0}, l1q[4]={0,0,0,0};
  const int* nr = nidx + p*KNB;
  #pragma unroll
  for(int k=0;k<KNB;k++){
    int idx = __builtin_nontemporal_load(nr + k);
    float4 nb = *(const float4*)(recA + ((size_t)((b<<LOGN)|idx))*32 + 16);
    float rx=nb.x-ct.x, ry=nb.y-ct.y, rz=nb.z-ct.z;
    float dd = __builtin_amdgcn_sqrtf(rx*rx+ry*ry+rz*rz);
    float fr[10] = {dd,rx,ry,rz,ct.x,ct.y,ct.z,nb.x,nb.y,nb.z};
    #pragma unroll
    for(int c=0;c<8;c++){
      float v = bl1[c];
      #pragma unroll
      for(int j=0;j<10;j++) v += WL1[c*10+j]*fr[j];
      l1s[c>>1]+=v; l1q[c>>1]+=v*v;
    }
  }
  __shared__ float lst[24];
  if(threadIdx.x < 24) lst[threadIdx.x] = 0.f;
  __syncthreads();
  int lane = threadIdx.x & 63;
  #pragma unroll
  for(int g=0; g<4; g++){
    float a1v = wred(s1s[g]), a2v = wred(s1q[g]);
    float d1v = wred(sss[g]), d2v = wred(ssq[g]);
    float e1v = wred(l1s[g]), e2v = wred(l1q[g]);
    if(lane==0){
      atomicAdd(&lst[ 0+g*2], a1v); atomicAdd(&lst[ 1+g*2], a2v);
      atomicAdd(&lst[ 8+g*2], d1v); atomicAdd(&lst[ 9+g*2], d2v);
      atomicAdd(&lst[16+g*2], e1v); atomicAdd(&lst[17+g*2], e2v);
    }
  }
  __syncthreads();
  if(threadIdx.x < 24){
    int stage = threadIdx.x >> 3;
    int g = (threadIdx.x >> 1) & 3;
    int w = threadIdx.x & 1;
    atomicAdd(ws + ((stage*4+b)*4+g)*128 + w*64 + (blockIdx.x&63), lst[threadIdx.x]);
  }
}

// ---------------- K2: att-pool 1 (inline lfa1, MFMA S^T, permlane softmax) ----------------
template<bool PAIR>
__global__ __launch_bounds__(256,8) void k2(
    const int* __restrict__ nidx,
    const float* __restrict__ WL1, const float* __restrict__ bl1,
    const float* __restrict__ Wa1,
    const float* __restrict__ Wm1, const float* __restrict__ bm1,
    const float* __restrict__ W2,  const float* __restrict__ b2,
    float* __restrict__ ws){
  const float* fin = ws + FIN_OFF;
  int b, nblk; xcd_map(blockIdx.x, b, nblk);
  int tid = threadIdx.x;
  int w = tid>>6, lane = tid&63, q = lane>>4, l15 = lane&15;
  int nbase = nblk*16 + w*4;
  int pA = (b<<LOGN) | (nbase + q);

  float scP[8], shP[8], scL[8], shL[8];
  #pragma unroll
  for(int c=0;c<8;c++){
    load_fin(fin, ST_MLP1,b,c, scP[c],shP[c]);
    load_fin(fin, ST_L1,  b,c, scL[c],shL[c]);
  }
  U16 bu; bu.u = make_uint4(0,0,0,0);
  if(q < 2){
    const float* wr = Wa1 + l15*16 + q*8;
    float4 w0 = *(const float4*)(wr);
    float4 w1 = *(const float4*)(wr+4);
    bu.u = make_uint4(pkbf(w0.x,w0.y), pkbf(w0.z,w0.w), pkbf(w1.x,w1.y), pkbf(w1.z,w1.w));
  }

  __shared__ unsigned char SB[4][WV_BYTES];
  __shared__ float lst[16];
  if(tid<16) lst[tid]=0.f;
  char* wb = (char*)SB[w];

  char* recA = (char*)(ws + RECA_OFF);
  char* recB = (char*)(ws + RECB_OFF);
  char* pairb = (char*)(ws + PAIR_OFF);

  // ---- phase A: lane = (point q, neighbor l15) ----
  int idx = __builtin_nontemporal_load(nidx + (size_t)pA*KNB + l15);
  const char* rp = recA + ((size_t)((b<<LOGN)|idx))*32;
  uint4 pk1  = *(const uint4*)(rp);
  float4 nb  = *(const float4*)(rp + 16);
  float4 ct  = *(const float4*)(recA + (size_t)pA*32 + 16);
  float rx=nb.x-ct.x, ry=nb.y-ct.y, rz=nb.z-ct.z;
  float dd = __builtin_amdgcn_sqrtf(rx*rx+ry*ry+rz*rz);
  float fr[10] = {dd,rx,ry,rz,ct.x,ct.y,ct.z,nb.x,nb.y,nb.z};
  float fx[8];
  #pragma unroll
  for(int c=0;c<8;c++){
    float v = bl1[c];
    #pragma unroll
    for(int j=0;j<10;j++) v += WL1[c*10+j]*fr[j];
    fx[c] = lrelu(v*scL[c]+shL[c]);
  }
  float xn[8];
  xn[0]=lrelu(blo(pk1.x)*scP[0]+shP[0]); xn[1]=lrelu(bhi(pk1.x)*scP[1]+shP[1]);
  xn[2]=lrelu(blo(pk1.y)*scP[2]+shP[2]); xn[3]=lrelu(bhi(pk1.y)*scP[3]+shP[3]);
  xn[4]=lrelu(blo(pk1.z)*scP[4]+shP[4]); xn[5]=lrelu(bhi(pk1.z)*scP[5]+shP[5]);
  xn[6]=lrelu(blo(pk1.w)*scP[6]+shP[6]); xn[7]=lrelu(bhi(pk1.w)*scP[7]+shP[7]);

  {
    uint4 d0 = make_uint4(pkbf(xn[0],xn[1]), pkbf(xn[2],xn[3]), pkbf(xn[4],xn[5]), pkbf(xn[6],xn[7]));
    uint4 d1 = make_uint4(pkbf(fx[0],fx[1]), pkbf(fx[2],fx[3]), pkbf(fx[4],fx[5]), pkbf(fx[6],fx[7]));
    char* base = wb + XB_OFF + q*256 + rowadr(l15);
    *(uint4*)(base)        = d0;
    *(uint4*)(base + 1024) = d1;
  }

  // lfa2 pre-GN values (lane=pair -> coalesced store; becomes l2pre for k3)
  float l2v[8];
  #pragma unroll
  for(int c=0;c<8;c++){
    float v = b2[c];
    #pragma unroll
    for(int j=0;j<8;j++) v += W2[c*8+j]*fx[j];
    l2v[c]=v;
  }
  if constexpr (PAIR){
    u32x4 lp2 = { pkbf(l2v[0],l2v[1]), pkbf(l2v[2],l2v[3]),
                  pkbf(l2v[4],l2v[5]), pkbf(l2v[6],l2v[7]) };
    __builtin_nontemporal_store(lp2, (u32x4*)(pairb + ((size_t)pA*KNB + l15)*16));
  }

  wave_fence();

  // ---- phase B: per point pt: MFMA S^T + permlane softmax + swizzled PV ----
  f32x4 cz = {0.f,0.f,0.f,0.f};
  int rxf = q & 2;
  const char* xc = wb + XB_OFF + (l15>>3)*1024 + (l15&7)*2;
  #pragma unroll
  for(int pt=0; pt<4; pt++){
    U16 afr; afr.u = make_uint4(0,0,0,0);
    if(q < 2) afr.u = *(const uint4*)(wb + XB_OFF + q*1024 + pt*256 + rowadr(l15));
    f32x4 cf = __builtin_amdgcn_mfma_f32_16x16x32_bf16(afr.s, bu.s, cz, 0,0,0);
    float mx = fmaxf(fmaxf(cf[0],cf[1]), fmaxf(cf[2],cf[3]));
    mx = x16max(mx); mx = x32max(mx);
    float pe0=__expf(cf[0]-mx), pe1=__expf(cf[1]-mx), pe2=__expf(cf[2]-mx), pe3=__expf(cf[3]-mx);
    float ps = pe0+pe1+pe2+pe3;
    ps = s16(ps); ps = s32(ps);
    const char* xe = xc + pt*256 + 64*q;
    float acc = pe0*bfu(*(const unsigned short*)(xe + 16*(0^rxf)))
              + pe1*bfu(*(const unsigned short*)(xe + 16*(1^rxf)))
              + pe2*bfu(*(const unsigned short*)(xe + 16*(2^rxf)))
              + pe3*bfu(*(const unsigned short*)(xe + 16*(3^rxf)));
    acc = s16(acc); acc = s32(acc);
    float agg = acc*__builtin_amdgcn_rcpf(ps);
    if(q==0) *(float*)(wb + AG_OFF + (pt*16+l15)*4) = agg;
  }

  // lfa2 stats
  float l2s[4]={0,0,0,0}, l2q[4]={0,0,0,0};
  #pragma unroll
  for(int c=0;c<8;c++){ l2s[c>>1]+=l2v[c]; l2q[c>>1]+=l2v[c]*l2v[c]; }

  wave_fence();

  // ---- phase D: point = q, out channel o = l15 (<8) ----
  float m1v = 0.f;
  if(l15 < 8){
    const float4* agp = (const float4*)(wb + AG_OFF + q*64);
    float4 A0=agp[0], A1=agp[1], A2=agp[2], A3=agp[3];
    const float4* wp = (const float4*)(Wm1 + l15*16);
    float4 W0=wp[0], W1_=wp[1], W2_=wp[2], W3=wp[3];
    float v = bm1[l15];
    v += W0.x*A0.x + W0.y*A0.y + W0.z*A0.z + W0.w*A0.w;
    v += W1_.x*A1.x + W1_.y*A1.y + W1_.z*A1.z + W1_.w*A1.w;
    v += W2_.x*A2.x + W2_.y*A2.y + W2_.z*A2.z + W2_.w*A2.w;
    v += W3.x*A3.x + W3.y*A3.y + W3.z*A3.z + W3.w*A3.w;
    m1v = v;
  }
  float vpart = __shfl_xor(m1v, 1);
  if(l15 < 8 && (l15&1)==0){
    unsigned u = pkbf(m1v, vpart);
    int pD = (b<<LOGN) | (nbase + q);
    *(unsigned*)(recB + (size_t)pD*32 + (l15>>1)*4) = u;
  }
  float m1s = s16(m1v); m1s = s32(m1s); m1s += __shfl_xor(m1s,1);
  float m1qv = m1v*m1v;
  float m1q = s16(m1qv); m1q = s32(m1q); m1q += __shfl_xor(m1q,1);

  __syncthreads();
  #pragma unroll
  for(int g=0;g<4;g++){
    float a=wred(l2s[g]), qq=wred(l2q[g]);
    if(lane==0){ atomicAdd(&lst[g*2],a); atomicAdd(&lst[g*2+1],qq); }
  }
  if(lane < 8 && (lane&1)==0){
    atomicAdd(&lst[8+(lane>>1)*2],   m1s);
    atomicAdd(&lst[8+(lane>>1)*2+1], m1q);
  }
  __syncthreads();
  if(tid<16){
    int half=tid>>3, g=(tid>>1)&3, wsel=tid&1;
    int stage = half? ST_M1 : ST_L2;
    atomicAdd(ws + ((stage*4+b)*4+g)*128 + wsel*64 + (blockIdx.x&63), lst[tid]);
  }
}

// ---------------- K3: att-pool 2 (pair-read l2pre, MFMA S^T, permlane softmax) ----------------
template<bool PAIR>
__global__ __launch_bounds__(256,8) void k3(
    const int* __restrict__ nidx,
    const float* __restrict__ WL1, const float* __restrict__ bl1,
    const float* __restrict__ W2,  const float* __restrict__ b2,
    const float* __restrict__ Wa2,
    const float* __restrict__ Wm2, const float* __restrict__ bm2,
    float* __restrict__ ws){
  const float* fin = ws + FIN_OFF;
  int b, nblk; xcd_map(blockIdx.x, b, nblk);
  int tid = threadIdx.x;
  int w = tid>>6, lane = tid&63, q = lane>>4, l15 = lane&15;
  int nbase = nblk*16 + w*4;
  int pA = (b<<LOGN) | (nbase + q);

  float scL[8], shL[8], scL2[8], shL2[8], scM[8], shM[8];
  #pragma unroll
  for(int c=0;c<8;c++){
    load_fin(fin, ST_L1, b,c, scL[c], shL[c]);
    load_fin(fin, ST_L2, b,c, scL2[c],shL2[c]);
    load_fin(fin, ST_M1, b,c, scM[c], shM[c]);
  }
  U16 bu; bu.u = make_uint4(0,0,0,0);
  if(q < 2){
    const float* wr = Wa2 + l15*16 + q*8;
    float4 w0 = *(const float4*)(wr);
    float4 w1 = *(const float4*)(wr+4);
    bu.u = make_uint4(pkbf(w0.x,w0.y), pkbf(w0.z,w0.w), pkbf(w1.x,w1.y), pkbf(w1.z,w1.w));
  }
  float wmr[16];
  {
    const float4* wp = (const float4*)(Wm2 + l15*16);
    float4 m0=wp[0], m1=wp[1], m2=wp[2], m3=wp[3];
    wmr[0]=m0.x; wmr[1]=m0.y; wmr[2]=m0.z; wmr[3]=m0.w;
    wmr[4]=m1.x; wmr[5]=m1.y; wmr[6]=m1.z; wmr[7]=m1.w;
    wmr[8]=m2.x; wmr[9]=m2.y; wmr[10]=m2.z; wmr[11]=m2.w;
    wmr[12]=m3.x; wmr[13]=m3.y; wmr[14]=m3.z; wmr[15]=m3.w;
  }

  __shared__ unsigned char SB[4][WV_BYTES];
  __shared__ float lst[8];
  if(tid<8) lst[tid]=0.f;
  char* wb = (char*)SB[w];

  char* recB = (char*)(ws + RECB_OFF);
  char* pairb = (char*)(ws + PAIR_OFF);
  float* prem2 = ws + PREM2_OFF;

  // ---- phase A ----
  int idx = __builtin_nontemporal_load(nidx + (size_t)pA*KNB + l15);
  const char* rp = recB + ((size_t)((b<<LOGN)|idx))*32;
  uint4 pm1 = *(const uint4*)(rp);
  float fx2[8];
  if constexpr (PAIR){
    u32x4 lp = __builtin_nontemporal_load(
        (const u32x4*)(pairb + ((size_t)pA*KNB + l15)*16));
    fx2[0]=lrelu(blo(lp.x)*scL2[0]+shL2[0]); fx2[1]=lrelu(bhi(lp.x)*scL2[1]+shL2[1]);
    fx2[2]=lrelu(blo(lp.y)*scL2[2]+shL2[2]); fx2[3]=lrelu(bhi(lp.y)*scL2[3]+shL2[3]);
    fx2[4]=lrelu(blo(lp.z)*scL2[4]+shL2[4]); fx2[5]=lrelu(bhi(lp.z)*scL2[5]+shL2[5]);
    fx2[6]=lrelu(blo(lp.w)*scL2[6]+shL2[6]); fx2[7]=lrelu(bhi(lp.w)*scL2[7]+shL2[7]);
  } else {
    float4 nb = *(const float4*)(rp + 16);
    float4 ct = *(const float4*)(recB + (size_t)pA*32 + 16);
    float rx=nb.x-ct.x, ry=nb.y-ct.y, rz=nb.z-ct.z;
    float dd = __builtin_amdgcn_sqrtf(rx*rx+ry*ry+rz*rz);
    float fr[10] = {dd,rx,ry,rz,ct.x,ct.y,ct.z,nb.x,nb.y,nb.z};
    float fx[8];
    #pragma unroll
    for(int c=0;c<8;c++){
      float v = bl1[c];
      #pragma unroll
      for(int j=0;j<10;j++) v += WL1[c*10+j]*fr[j];
      fx[c] = lrelu(v*scL[c]+shL[c]);
    }
    #pragma unroll
    for(int c=0;c<8;c++){
      float v = b2[c];
      #pragma unroll
      for(int j=0;j<8;j++) v += W2[c*8+j]*fx[j];
      fx2[c] = lrelu(v*scL2[c]+shL2[c]);
    }
  }
  float xn[8];
  xn[0]=lrelu(blo(pm1.x)*scM[0]+shM[0]); xn[1]=lrelu(bhi(pm1.x)*scM[1]+shM[1]);
  xn[2]=lrelu(blo(pm1.y)*scM[2]+shM[2]); xn[3]=lrelu(bhi(pm1.y)*scM[3]+shM[3]);
  xn[4]=lrelu(blo(pm1.z)*scM[4]+shM[4]); xn[5]=lrelu(bhi(pm1.z)*scM[5]+shM[5]);
  xn[6]=lrelu(blo(pm1.w)*scM[6]+shM[6]); xn[7]=lrelu(bhi(pm1.w)*scM[7]+shM[7]);

  {
    uint4 d0 = make_uint4(pkbf(xn[0],xn[1]), pkbf(xn[2],xn[3]), pkbf(xn[4],xn[5]), pkbf(xn[6],xn[7]));
    uint4 d1 = make_uint4(pkbf(fx2[0],fx2[1]), pkbf(fx2[2],fx2[3]), pkbf(fx2[4],fx2[5]), pkbf(fx2[6],fx2[7]));
    char* base = wb + XB_OFF + q*256 + rowadr(l15);
    *(uint4*)(base)        = d0;
    *(uint4*)(base + 1024) = d1;
  }

  wave_fence();

  f32x4 cz = {0.f,0.f,0.f,0.f};
  int rxf = q & 2;
  const char* xc = wb + XB_OFF + (l15>>3)*1024 + (l15&7)*2;
  #pragma unroll
  for(int pt=0; pt<4; pt++){
    U16 afr; afr.u = make_uint4(0,0,0,0);
    if(q < 2) afr.u = *(const uint4*)(wb + XB_OFF + q*1024 + pt*256 + rowadr(l15));
    f32x4 cf = __builtin_amdgcn_mfma_f32_16x16x32_bf16(afr.s, bu.s, cz, 0,0,0);
    float mx = fmaxf(fmaxf(cf[0],cf[1]), fmaxf(cf[2],cf[3]));
    mx = x16max(mx); mx = x32max(mx);
    float pe0=__expf(cf[0]-mx), pe1=__expf(cf[1]-mx), pe2=__expf(cf[2]-mx), pe3=__expf(cf[3]-mx);
    float ps = pe0+pe1+pe2+pe3;
    ps = s16(ps); ps = s32(ps);
    const char* xe = xc + pt*256 + 64*q;
    float acc = pe0*bfu(*(const unsigned short*)(xe + 16*(0^rxf)))
              + pe1*bfu(*(const unsigned short*)(xe + 16*(1^rxf)))
              + pe2*bfu(*(const unsigned short*)(xe + 16*(2^rxf)))
              + pe3*bfu(*(const unsigned short*)(xe + 16*(3^rxf)));
    acc = s16(acc); acc = s32(acc);
    float agg = acc*__builtin_amdgcn_rcpf(ps);
    if(q==0) *(float*)(wb + AG_OFF + (pt*16+l15)*4) = agg;
  }

  wave_fence();

  // ---- phase D: point = q, out channel o = l15 ----
  float v;
  {
    const float4* agp = (const float4*)(wb + AG_OFF + q*64);
    float4 A0=agp[0], A1=agp[1], A2=agp[2], A3=agp[3];
    v = bm2[l15];
    v += wmr[0]*A0.x + wmr[1]*A0.y + wmr[2]*A0.z + wmr[3]*A0.w;
    v += wmr[4]*A1.x + wmr[5]*A1.y + wmr[6]*A1.z + wmr[7]*A1.w;
    v += wmr[8]*A2.x + wmr[9]*A2.y + wmr[10]*A2.z + wmr[11]*A2.w;
    v += wmr[12]*A3.x + wmr[13]*A3.y + wmr[14]*A3.z + wmr[15]*A3.w;
  }
  int pD = (b<<LOGN) | (nbase + q);
  __builtin_nontemporal_store(v, prem2 + (size_t)pD*16 + l15);

  float s = s16(v);  s = s32(s);  s += __shfl_xor(s,1);  s += __shfl_xor(s,2);
  float qv = v*v;
  float qq = s16(qv); qq = s32(qq); qq += __shfl_xor(qq,1); qq += __shfl_xor(qq,2);

  __syncthreads();
  if(lane < 16 && (lane&3)==0){
    atomicAdd(&lst[(lane>>2)*2],   s);
    atomicAdd(&lst[(lane>>2)*2+1], qq);
  }
  __syncthreads();
  if(tid<8){
    int g=(tid>>1)&3, wsel=tid&1;
    atomicAdd(ws + ((ST_M2*4+b)*4+g)*128 + wsel*64 + (blockIdx.x&63), lst[tid]);
  }
}

// ---------------- K4: stats of mlp2 output ----------------
__global__ __launch_bounds__(256) void k4(
    const float* __restrict__ Wo,  const float* __restrict__ bo,
    float* __restrict__ ws){
  const float* fin = ws + FIN_OFF;
  int b=blockIdx.y; int n=blockIdx.x*256+threadIdx.x; int p=(b<<LOGN)|n;
  float scM[16], shM[16];
  #pragma unroll
  for(int c=0;c<16;c++) load_fin(fin, ST_M2, b, c, scM[c], shM[c]);
  const f32x4* pm = (const f32x4*)(ws + PREM2_OFF) + (size_t)p*4;
  float fa[16];
  #pragma unroll
  for(int i=0;i<4;i++){
    f32x4 v4 = __builtin_nontemporal_load(pm + i);
    fa[i*4+0]=lrelu(v4.x*scM[i*4+0]+shM[i*4+0]);
    fa[i*4+1]=lrelu(v4.y*scM[i*4+1]+shM[i*4+1]);
    fa[i*4+2]=lrelu(v4.z*scM[i*4+2]+shM[i*4+2]);
    fa[i*4+3]=lrelu(v4.w*scM[i*4+3]+shM[i*4+3]);
  }
  float sos[4]={0,0,0,0}, soq[4]={0,0,0,0};
  #pragma unroll
  for(int o=0;o<32;o++){
    float v=bo[o];
    #pragma unroll
    for(int c=0;c<16;c++) v += Wo[o*16+c]*fa[c];
    sos[o>>3]+=v; soq[o>>3]+=v*v;
  }
  __shared__ float lst[8];
  if(threadIdx.x<8) lst[threadIdx.x]=0.f;
  __syncthreads();
  int lane = threadIdx.x & 63;
  #pragma unroll
  for(int g=0;g<4;g++){
    float a=wred(sos[g]), q=wred(soq[g]);
    if(lane==0){ atomicAdd(&lst[g*2],a); atomicAdd(&lst[g*2+1],q); }
  }
  __syncthreads();
  if(threadIdx.x<8){
    int g=(threadIdx.x>>1)&3, w=threadIdx.x&1;
    atomicAdd(ws + ((ST_OUT*4+b)*4+g)*128 + w*64 + (blockIdx.x&63), lst[threadIdx.x]);
  }
}

// ---------------- K5: final out ----------------
__global__ __launch_bounds__(256) void k5(
    const float* __restrict__ feat,
    const float* __restrict__ Wo,  const float* __restrict__ bo,
    const float* __restrict__ Wsk, const float* __restrict__ bsk,
    const float* __restrict__ ws, float* __restrict__ out){
  const float* fin = ws + FIN_OFF;
  int b=blockIdx.y; int n=blockIdx.x*256+threadIdx.x; int p=(b<<LOGN)|n;
  float scM[16], shM[16];
  #pragma unroll
  for(int c=0;c<16;c++) load_fin(fin, ST_M2, b, c, scM[c], shM[c]);
  const f32x4* pm = (const f32x4*)(ws + PREM2_OFF) + (size_t)p*4;
  float fa[16];
  #pragma unroll
  for(int i=0;i<4;i++){
    f32x4 v4 = __builtin_nontemporal_load(pm + i);
    fa[i*4+0]=lrelu(v4.x*scM[i*4+0]+shM[i*4+0]);
    fa[i*4+1]=lrelu(v4.y*scM[i*4+1]+shM[i*4+1]);
    fa[i*4+2]=lrelu(v4.z*scM[i*4+2]+shM[i*4+2]);
    fa[i*4+3]=lrelu(v4.w*scM[i*4+3]+shM[i*4+3]);
  }
  float f[8];
  #pragma unroll
  for(int c=0;c<8;c++) f[c]=__builtin_nontemporal_load(feat + (b*8+c)*NPTS + n);
  #pragma unroll
  for(int o=0;o<32;o++){
    float to = bo[o];
    #pragma unroll
    for(int c=0;c<16;c++) to += Wo[o*16+c]*fa[c];
    float ts = bsk[o];
    #pragma unroll
    for(int j=0;j<8;j++) ts += Wsk[o*8+j]*f[j];
    float scO, shO, scS, shS;
    load_fin(fin, ST_OUT,  b, o, scO, shO);
    load_fin(fin, ST_SKIP, b, o, scS, shS);
    float v = to*scO+shO + ts*scS+shS;
    __builtin_nontemporal_store(lrelu(v), out + (size_t)(b*32+o)*NPTS + n);
  }
}

extern "C" void kernel_launch(void* const* d_in, const int* in_sizes, int n_in,
                              void* d_out, int out_size, void* d_ws, size_t ws_size,
                              hipStream_t stream){
  (void)in_sizes; (void)n_in; (void)out_size;
  const float* feat=(const float*)d_in[0];
  const float* xyz =(const float*)d_in[1];
  const int*   nidx=(const int*)d_in[2];
  const float* W1  =(const float*)d_in[3];
  const float* b1  =(const float*)d_in[4];
  const float* g1  =(const float*)d_in[5];
  const float* be1 =(const float*)d_in[6];
  const float* WL1 =(const float*)d_in[7];
  const float* bl1 =(const float*)d_in[8];
  const float* gL1 =(const float*)d_in[9];
  const float* beL1=(const float*)d_in[10];
  const float* Wa1 =(const float*)d_in[11];
  const float* Wm1 =(const float*)d_in[12];
  const float* bm1 =(const float*)d_in[13];
  const float* gm1 =(const float*)d_in[14];
  const float* bem1=(const float*)d_in[15];
  const float* W2  =(const float*)d_in[16];
  const float* b2  =(const float*)d_in[17];
  const float* gL2 =(const float*)d_in[18];
  const float* beL2=(const float*)d_in[19];
  const float* Wa2 =(const float*)d_in[20];
  const float* Wm2 =(const float*)d_in[21];
  const float* bm2 =(const float*)d_in[22];
  const float* gm2 =(const float*)d_in[23];
  const float* bem2=(const float*)d_in[24];
  const float* Wo  =(const float*)d_in[25];
  const float* bo  =(const float*)d_in[26];
  const float* go  =(const float*)d_in[27];
  const float* beo =(const float*)d_in[28];
  const float* Wsk =(const float*)d_in[29];
  const float* bsk =(const float*)d_in[30];
  const float* gsk =(const float*)d_in[31];
  const float* besk=(const float*)d_in[32];
  float* ws=(float*)d_ws;
  float* out=(float*)d_out;

  bool usePair = (ws_size >= NEED_BYTES);

  hipMemsetAsync(d_ws, 0, STAT_F*sizeof(float), stream);
  k_pack<<<dim3(1024),dim3(256),0,stream>>>(xyz, ws);
  k1<<<dim3(1024),dim3(256),0,stream>>>(feat, nidx, W1,b1, Wsk,bsk, WL1,bl1, ws);
  kfA<<<dim3(3),dim3(128),0,stream>>>(ws, g1,be1, gL1,beL1, gsk,besk);
  if(usePair)
    k2<true><<<dim3(16384),dim3(256),0,stream>>>(nidx, WL1,bl1, Wa1, Wm1,bm1, W2,b2, ws);
  else
    k2<false><<<dim3(16384),dim3(256),0,stream>>>(nidx, WL1,bl1, Wa1, Wm1,bm1, W2,b2, ws);
  kfB<<<dim3(2),dim3(128),0,stream>>>(ws, gm1,bem1, gL2,beL2);
  if(usePair)
    k3<true><<<dim3(16384),dim3(256),0,stream>>>(nidx, WL1,bl1, W2,b2, Wa2, Wm2,bm2, ws);
  else
    k3<false><<<dim3(16384),dim3(256),0,stream>>>(nidx, WL1,bl1, W2,b2, Wa2, Wm2,bm2, ws);
  kfC<<<dim3(1),dim3(128),0,stream>>>(ws, gm2,bem2);
  k4<<<dim3(256,4),dim3(256),0,stream>>>(Wo,bo, ws);
  kfD<<<dim3(1),dim3(128),0,stream>>>(ws, go,beo);
  k5<<<dim3(256,4),dim3(256),0,stream>>>(feat, Wo,bo, Wsk,bsk, ws, out);
}

// Round 15
// 232.488 us; speedup vs baseline: 1.7029x; 1.1591x over previous
//
#include <hip/hip_runtime.h>
#include <hip/hip_bf16.h>

#define NPTS 65536
#define LOGN 16
#define KNB 16
#define NEGS 0.2f
#define EPSV 1e-5f

// GN stages
#define ST_MLP1 0
#define ST_SKIP 1
#define ST_L1   2
#define ST_M1   3
#define ST_L2   4
#define ST_M2   5
#define ST_OUT  6

// ws layout (floats): raw stats | fin | recA (32B/pt) | recB (32B/pt) | prem2 | pairbuf
#define STAT_F   14336                       // 7*4*4*128
#define FIN_OFF  14336
#define RECA_OFF 16384
#define RECB_OFF  (RECA_OFF + 4*NPTS*8)
#define PREM2_OFF (RECB_OFF + 4*NPTS*8)
#define PAIR_OFF  (PREM2_OFF + 4*NPTS*16)
#define PAIR_FLOATS ((size_t)4*NPTS*KNB*4)
#define NEED_BYTES (((size_t)PAIR_OFF + PAIR_FLOATS)*4)

typedef __attribute__((ext_vector_type(8))) short short8;
typedef __attribute__((ext_vector_type(4))) float f32x4;
typedef __attribute__((ext_vector_type(4))) unsigned u32x4;

union U16 { uint4 u; short8 s; };

__device__ __forceinline__ float lrelu(float v){ return fmaxf(v, v*NEGS); }

// cross-lane helpers (shfl-based; A/B-proven vs permlane in R10/R14)
__device__ __forceinline__ float s16(float v){ return v + __shfl_xor(v,16); }
__device__ __forceinline__ float s32(float v){ return v + __shfl_xor(v,32); }
__device__ __forceinline__ float x16max(float v){ return fmaxf(v, __shfl_xor(v,16)); }
__device__ __forceinline__ float x32max(float v){ return fmaxf(v, __shfl_xor(v,32)); }

__device__ __forceinline__ float wred(float v){
  #pragma unroll
  for(int off=32; off>0; off>>=1) v += __shfl_xor(v, off, 64);
  return v;
}

__device__ __forceinline__ void wave_fence(){
  __builtin_amdgcn_sched_barrier(0);
  asm volatile("s_waitcnt lgkmcnt(0)" ::: "memory");
  __builtin_amdgcn_sched_barrier(0);
}

__device__ __forceinline__ void load_fin(const float* fin, int stage, int b, int c,
                                         float& sc, float& sh){
  const float* fp = fin + ((stage*4+b)*32 + c)*2;
  sc = fp[0]; sh = fp[1];
}

__device__ __forceinline__ unsigned pkbf(float a, float b){
  __hip_bfloat162 h = __float22bfloat162_rn(make_float2(a,b));
  union{ __hip_bfloat162 h2; unsigned u; } cv; cv.h2 = h; return cv.u;
}
__device__ __forceinline__ float blo(unsigned d){ return __builtin_bit_cast(float, d<<16); }
__device__ __forceinline__ float bhi(unsigned d){ return __builtin_bit_cast(float, d & 0xffff0000u); }
__device__ __forceinline__ float bfu(unsigned short h){ return __builtin_bit_cast(float, ((unsigned)h)<<16); }

// XB row address swizzle: rows 8-15 get bit5 flipped -> PV q-groups hit disjoint banks
__device__ __forceinline__ int rowadr(int row){ return (row*16) ^ ((row&8)<<2); }

// per-wave LDS region (one tile): XB planes (2 x 1024B) + AG (256B)
#define XB_OFF 0
#define AG_OFF 2048
#define WV_BYTES 2304

// batch<->XCD affinity (1024-block point-parallel kernels)
__device__ __forceinline__ void xcd_map(int bid, int& b, int& nblk){
  int xcd = bid & 7;
  b = xcd >> 1;
  nblk = ((bid >> 3) << 1) | (xcd & 1);
}

// ---------------- K0: pack xyz -> recA.xyz + recB.xyz ----------------
__global__ __launch_bounds__(256) void k_pack(const float* __restrict__ xyz,
                                              float* __restrict__ ws){
  int p = blockIdx.x*256 + threadIdx.x;
  int b = p >> LOGN, n = p & (NPTS-1);
  const float* xb = xyz + b*3*NPTS + n;
  float4 v = make_float4(xb[0], xb[NPTS], xb[2*NPTS], 0.f);
  *(float4*)((char*)(ws + RECA_OFF) + (size_t)p*32 + 16) = v;
  *(float4*)((char*)(ws + RECB_OFF) + (size_t)p*32 + 16) = v;
}

// ---------------- fin: raw slots -> (scale,shift) per channel ----------------
__device__ void fin_stage(const float* __restrict__ ws, float* __restrict__ fin,
                          int stage, int nch, float cnt,
                          const float* __restrict__ gamma, const float* __restrict__ beta){
  int t = threadIdx.x;
  if(t >= 4*nch) return;
  int b = t / nch, c = t - b*nch;
  int g = c / (nch/4);
  const float* sl = ws + ((stage*4+b)*4+g)*128;
  float s=0.f, q=0.f;
  #pragma unroll 8
  for(int i=0;i<64;i++){ s += sl[i]; q += sl[64+i]; }
  float mean = s/cnt;
  float var  = q/cnt - mean*mean;
  float inv  = rsqrtf(var + EPSV);
  float sc = inv*gamma[c];
  float sh = beta[c] - mean*sc;
  float* fp = fin + ((stage*4+b)*32 + c)*2;
  fp[0]=sc; fp[1]=sh;
}

__global__ __launch_bounds__(128) void kfA(float* __restrict__ ws,
    const float* g1, const float* be1, const float* gL1, const float* beL1,
    const float* gsk, const float* besk){
  if(blockIdx.x==0)      fin_stage(ws, ws+FIN_OFF, ST_MLP1, 8,  2.0f*NPTS,      g1, be1);
  else if(blockIdx.x==1) fin_stage(ws, ws+FIN_OFF, ST_L1,   8,  2.0f*NPTS*KNB,  gL1, beL1);
  else                   fin_stage(ws, ws+FIN_OFF, ST_SKIP, 32, 8.0f*NPTS,      gsk, besk);
}
__global__ __launch_bounds__(128) void kfB(float* __restrict__ ws,
    const float* gm1, const float* bem1, const float* gL2, const float* beL2){
  if(blockIdx.x==0) fin_stage(ws, ws+FIN_OFF, ST_M1, 8, 2.0f*NPTS,     gm1, bem1);
  else              fin_stage(ws, ws+FIN_OFF, ST_L2, 8, 2.0f*NPTS*KNB, gL2, beL2);
}
__global__ __launch_bounds__(128) void kfC(float* __restrict__ ws,
    const float* gm2, const float* bem2){
  fin_stage(ws, ws+FIN_OFF, ST_M2, 16, 4.0f*NPTS, gm2, bem2);
}
__global__ __launch_bounds__(128) void kfD(float* __restrict__ ws,
    const float* go, const float* beo){
  fin_stage(ws, ws+FIN_OFF, ST_OUT, 32, 8.0f*NPTS, go, beo);
}

// ---------------- K1: mlp1 pre(bf16 in recA) + stats; skip stats; lfa1 stats ----------------
__global__ __launch_bounds__(256) void k1(
    const float* __restrict__ feat, const int* __restrict__ nidx,
    const float* __restrict__ W1,  const float* __restrict__ b1,
    const float* __restrict__ Ws,  const float* __restrict__ bs,
    const float* __restrict__ WL1, const float* __restrict__ bl1,
    float* __restrict__ ws){
  int b, nblk; xcd_map(blockIdx.x, b, nblk);
  int n = nblk*256 + threadIdx.x;
  int p = (b<<LOGN) | n;
  char* recA = (char*)(ws + RECA_OFF);
  float f[8];
  #pragma unroll
  for(int c=0;c<8;c++) f[c] = __builtin_nontemporal_load(feat + (b*8+c)*NPTS + n);

  float s1s[4]={0,0,0,0}, s1q[4]={0,0,0,0};
  float pv[8];
  #pragma unroll
  for(int c=0;c<8;c++){
    float v = b1[c];
    #pragma unroll
    for(int j=0;j<8;j++) v += W1[c*8+j]*f[j];
    pv[c]=v;
    s1s[c>>1]+=v; s1q[c>>1]+=v*v;
  }
  uint4 pk = make_uint4(pkbf(pv[0],pv[1]), pkbf(pv[2],pv[3]),
                        pkbf(pv[4],pv[5]), pkbf(pv[6],pv[7]));
  *(uint4*)(recA + (size_t)p*32) = pk;

  float sss[4]={0,0,0,0}, ssq[4]={0,0,0,0};
  #pragma unroll
  for(int o=0;o<32;o++){
    float v = bs[o];
    #pragma unroll
    for(int j=0;j<8;j++) v += Ws[o*8+j]*f[j];
    sss[o>>3]+=v; ssq[o>>3]+=v*v;
  }
  float4 ct = *(const float4*)(recA + (size_t)p*32 + 16);
  float l1s[4]={0,0,0,0}, l1q[4]={0,0,0,0};
  const int* nr = nidx + p*KNB;
  #pragma unroll
  for(int k=0;k<KNB;k++){
    int idx = __builtin_nontemporal_load(nr + k);
    float4 nb = *(const float4*)(recA + ((size_t)((b<<LOGN)|idx))*32 + 16);
    float rx=nb.x-ct.x, ry=nb.y-ct.y, rz=nb.z-ct.z;
    float dd = __builtin_amdgcn_sqrtf(rx*rx+ry*ry+rz*rz);
    float fr[10] = {dd,rx,ry,rz,ct.x,ct.y,ct.z,nb.x,nb.y,nb.z};
    #pragma unroll
    for(int c=0;c<8;c++){
      float v = bl1[c];
      #pragma unroll
      for(int j=0;j<10;j++) v += WL1[c*10+j]*fr[j];
      l1s[c>>1]+=v; l1q[c>>1]+=v*v;
    }
  }
  __shared__ float lst[24];
  if(threadIdx.x < 24) lst[threadIdx.x] = 0.f;
  __syncthreads();
  int lane = threadIdx.x & 63;
  #pragma unroll
  for(int g=0; g<4; g++){
    float a1v = wred(s1s[g]), a2v = wred(s1q[g]);
    float d1v = wred(sss[g]), d2v = wred(ssq[g]);
    float e1v = wred(l1s[g]), e2v = wred(l1q[g]);
    if(lane==0){
      atomicAdd(&lst[ 0+g*2], a1v); atomicAdd(&lst[ 1+g*2], a2v);
      atomicAdd(&lst[ 8+g*2], d1v); atomicAdd(&lst[ 9+g*2], d2v);
      atomicAdd(&lst[16+g*2], e1v); atomicAdd(&lst[17+g*2], e2v);
    }
  }
  __syncthreads();
  if(threadIdx.x < 24){
    int stage = threadIdx.x >> 3;
    int g = (threadIdx.x >> 1) & 3;
    int w = threadIdx.x & 1;
    atomicAdd(ws + ((stage*4+b)*4+g)*128 + w*64 + (blockIdx.x&63), lst[threadIdx.x]);
  }
}

// ---------------- K2: att-pool 1, ILP=2 tiles/wave, double-buffered LDS ----------------
template<bool PAIR>
__global__ __launch_bounds__(256,6) void k2(
    const int* __restrict__ nidx,
    const float* __restrict__ WL1, const float* __restrict__ bl1,
    const float* __restrict__ Wa1,
    const float* __restrict__ Wm1, const float* __restrict__ bm1,
    const float* __restrict__ W2,  const float* __restrict__ b2,
    float* __restrict__ ws){
  const float* fin = ws + FIN_OFF;
  int bid = blockIdx.x;
  int xcd = bid & 7;
  int b = xcd >> 1;
  int j = ((bid >> 3) << 1) | (xcd & 1);     // 0..2047
  int tid = threadIdx.x;
  int w = tid>>6, lane = tid&63, q = lane>>4, l15 = lane&15;
  int nbase0 = (2*j  )*16 + w*4;
  int nbase1 = (2*j+1)*16 + w*4;
  int pA0 = (b<<LOGN) | (nbase0 + q);
  int pA1 = (b<<LOGN) | (nbase1 + q);

  float scP[8], shP[8], scL[8], shL[8];
  #pragma unroll
  for(int c=0;c<8;c++){
    load_fin(fin, ST_MLP1,b,c, scP[c],shP[c]);
    load_fin(fin, ST_L1,  b,c, scL[c],shL[c]);
  }
  U16 bu; bu.u = make_uint4(0,0,0,0);
  if(q < 2){
    const float* wr = Wa1 + l15*16 + q*8;
    float4 w0 = *(const float4*)(wr);
    float4 w1 = *(const float4*)(wr+4);
    bu.u = make_uint4(pkbf(w0.x,w0.y), pkbf(w0.z,w0.w), pkbf(w1.x,w1.y), pkbf(w1.z,w1.w));
  }

  __shared__ unsigned char SB[4][2*WV_BYTES];
  __shared__ float lst[16];
  if(tid<16) lst[tid]=0.f;
  char* wb = (char*)SB[w];

  char* recA = (char*)(ws + RECA_OFF);
  char* recB = (char*)(ws + RECB_OFF);
  char* pairb = (char*)(ws + PAIR_OFF);

  // ---- phase A: both tiles; issue all gathers up front ----
  int pAt[2] = {pA0, pA1};
  int idxT[2];
  #pragma unroll
  for(int t=0;t<2;t++)
    idxT[t] = __builtin_nontemporal_load(nidx + (size_t)pAt[t]*KNB + l15);
  uint4 pk1T[2]; float4 nbT[2], ctT[2];
  #pragma unroll
  for(int t=0;t<2;t++){
    const char* rp = recA + ((size_t)((b<<LOGN)|idxT[t]))*32;
    pk1T[t] = *(const uint4*)(rp);
    nbT[t]  = *(const float4*)(rp + 16);
    ctT[t]  = *(const float4*)(recA + (size_t)pAt[t]*32 + 16);
  }

  float l2s[4]={0,0,0,0}, l2q[4]={0,0,0,0};
  #pragma unroll
  for(int t=0;t<2;t++){
    float4 nb = nbT[t], ct = ctT[t];
    float rx=nb.x-ct.x, ry=nb.y-ct.y, rz=nb.z-ct.z;
    float dd = __builtin_amdgcn_sqrtf(rx*rx+ry*ry+rz*rz);
    float fr[10] = {dd,rx,ry,rz,ct.x,ct.y,ct.z,nb.x,nb.y,nb.z};
    float fx[8];
    #pragma unroll
    for(int c=0;c<8;c++){
      float v = bl1[c];
      #pragma unroll
      for(int jj=0;jj<10;jj++) v += WL1[c*10+jj]*fr[jj];
      fx[c] = lrelu(v*scL[c]+shL[c]);
    }
    uint4 pk1 = pk1T[t];
    float xn[8];
    xn[0]=lrelu(blo(pk1.x)*scP[0]+shP[0]); xn[1]=lrelu(bhi(pk1.x)*scP[1]+shP[1]);
    xn[2]=lrelu(blo(pk1.y)*scP[2]+shP[2]); xn[3]=lrelu(bhi(pk1.y)*scP[3]+shP[3]);
    xn[4]=lrelu(blo(pk1.z)*scP[4]+shP[4]); xn[5]=lrelu(bhi(pk1.z)*scP[5]+shP[5]);
    xn[6]=lrelu(blo(pk1.w)*scP[6]+shP[6]); xn[7]=lrelu(bhi(pk1.w)*scP[7]+shP[7]);

    {
      uint4 d0 = make_uint4(pkbf(xn[0],xn[1]), pkbf(xn[2],xn[3]), pkbf(xn[4],xn[5]), pkbf(xn[6],xn[7]));
      uint4 d1 = make_uint4(pkbf(fx[0],fx[1]), pkbf(fx[2],fx[3]), pkbf(fx[4],fx[5]), pkbf(fx[6],fx[7]));
      char* base = wb + t*WV_BYTES + XB_OFF + q*256 + rowadr(l15);
      *(uint4*)(base)        = d0;
      *(uint4*)(base + 1024) = d1;
    }

    float l2v[8];
    #pragma unroll
    for(int c=0;c<8;c++){
      float v = b2[c];
      #pragma unroll
      for(int jj=0;jj<8;jj++) v += W2[c*8+jj]*fx[jj];
      l2v[c]=v;
      l2s[c>>1]+=v; l2q[c>>1]+=v*v;
    }
    if constexpr (PAIR){
      u32x4 lp2 = { pkbf(l2v[0],l2v[1]), pkbf(l2v[2],l2v[3]),
                    pkbf(l2v[4],l2v[5]), pkbf(l2v[6],l2v[7]) };
      __builtin_nontemporal_store(lp2, (u32x4*)(pairb + ((size_t)pAt[t]*KNB + l15)*16));
    }
  }

  wave_fence();

  // ---- phase B: both tiles, 4 MFMAs each ----
  f32x4 cz = {0.f,0.f,0.f,0.f};
  int rxf = q & 2;
  #pragma unroll
  for(int t=0;t<2;t++){
    const char* xc = wb + t*WV_BYTES + XB_OFF + (l15>>3)*1024 + (l15&7)*2;
    #pragma unroll
    for(int pt=0; pt<4; pt++){
      U16 afr; afr.u = make_uint4(0,0,0,0);
      if(q < 2) afr.u = *(const uint4*)(wb + t*WV_BYTES + XB_OFF + q*1024 + pt*256 + rowadr(l15));
      f32x4 cf = __builtin_amdgcn_mfma_f32_16x16x32_bf16(afr.s, bu.s, cz, 0,0,0);
      float mx = fmaxf(fmaxf(cf[0],cf[1]), fmaxf(cf[2],cf[3]));
      mx = x16max(mx); mx = x32max(mx);
      float pe0=__expf(cf[0]-mx), pe1=__expf(cf[1]-mx), pe2=__expf(cf[2]-mx), pe3=__expf(cf[3]-mx);
      float ps = pe0+pe1+pe2+pe3;
      ps = s16(ps); ps = s32(ps);
      const char* xe = xc + pt*256 + 64*q;
      float acc = pe0*bfu(*(const unsigned short*)(xe + 16*(0^rxf)))
                + pe1*bfu(*(const unsigned short*)(xe + 16*(1^rxf)))
                + pe2*bfu(*(const unsigned short*)(xe + 16*(2^rxf)))
                + pe3*bfu(*(const unsigned short*)(xe + 16*(3^rxf)));
      acc = s16(acc); acc = s32(acc);
      float agg = acc*__builtin_amdgcn_rcpf(ps);
      if(q==0) *(float*)(wb + t*WV_BYTES + AG_OFF + (pt*16+l15)*4) = agg;
    }
  }

  wave_fence();

  // ---- phase D: both tiles ----
  float m1as=0.f, m1aq=0.f;
  float wmr[16]; float bm1v = 0.f;
  if(l15 < 8){
    const float4* wp = (const float4*)(Wm1 + l15*16);
    float4 m0=wp[0], m1=wp[1], m2=wp[2], m3=wp[3];
    wmr[0]=m0.x; wmr[1]=m0.y; wmr[2]=m0.z; wmr[3]=m0.w;
    wmr[4]=m1.x; wmr[5]=m1.y; wmr[6]=m1.z; wmr[7]=m1.w;
    wmr[8]=m2.x; wmr[9]=m2.y; wmr[10]=m2.z; wmr[11]=m2.w;
    wmr[12]=m3.x; wmr[13]=m3.y; wmr[14]=m3.z; wmr[15]=m3.w;
    bm1v = bm1[l15];
  }
  #pragma unroll
  for(int t=0;t<2;t++){
    float m1v = 0.f;
    if(l15 < 8){
      const float4* agp = (const float4*)(wb + t*WV_BYTES + AG_OFF + q*64);
      float4 A0=agp[0], A1=agp[1], A2=agp[2], A3=agp[3];
      float v = bm1v;
      v += wmr[0]*A0.x + wmr[1]*A0.y + wmr[2]*A0.z + wmr[3]*A0.w;
      v += wmr[4]*A1.x + wmr[5]*A1.y + wmr[6]*A1.z + wmr[7]*A1.w;
      v += wmr[8]*A2.x + wmr[9]*A2.y + wmr[10]*A2.z + wmr[11]*A2.w;
      v += wmr[12]*A3.x + wmr[13]*A3.y + wmr[14]*A3.z + wmr[15]*A3.w;
      m1v = v;
    }
    float vpart = __shfl_xor(m1v, 1);
    if(l15 < 8 && (l15&1)==0){
      unsigned u = pkbf(m1v, vpart);
      *(unsigned*)(recB + (size_t)pAt[t]*32 + (l15>>1)*4) = u;
    }
    m1as += m1v; m1aq += m1v*m1v;
  }
  float m1s = s16(m1as); m1s = s32(m1s); m1s += __shfl_xor(m1s,1);
  float m1q = s16(m1aq); m1q = s32(m1q); m1q += __shfl_xor(m1q,1);

  __syncthreads();
  #pragma unroll
  for(int g=0;g<4;g++){
    float a=wred(l2s[g]), qq=wred(l2q[g]);
    if(lane==0){ atomicAdd(&lst[g*2],a); atomicAdd(&lst[g*2+1],qq); }
  }
  if(lane < 8 && (lane&1)==0){
    atomicAdd(&lst[8+(lane>>1)*2],   m1s);
    atomicAdd(&lst[8+(lane>>1)*2+1], m1q);
  }
  __syncthreads();
  if(tid<16){
    int half=tid>>3, g=(tid>>1)&3, wsel=tid&1;
    int stage = half? ST_M1 : ST_L2;
    atomicAdd(ws + ((stage*4+b)*4+g)*128 + wsel*64 + (bid&63), lst[tid]);
  }
}

// ---------------- K3: att-pool 2, ILP=2 tiles/wave ----------------
template<bool PAIR>
__global__ __launch_bounds__(256,6) void k3(
    const int* __restrict__ nidx,
    const float* __restrict__ WL1, const float* __restrict__ bl1,
    const float* __restrict__ W2,  const float* __restrict__ b2,
    const float* __restrict__ Wa2,
    const float* __restrict__ Wm2, const float* __restrict__ bm2,
    float* __restrict__ ws){
  const float* fin = ws + FIN_OFF;
  int bid = blockIdx.x;
  int xcd = bid & 7;
  int b = xcd >> 1;
  int j = ((bid >> 3) << 1) | (xcd & 1);
  int tid = threadIdx.x;
  int w = tid>>6, lane = tid&63, q = lane>>4, l15 = lane&15;
  int pAt[2];
  pAt[0] = (b<<LOGN) | ((2*j  )*16 + w*4 + q);
  pAt[1] = (b<<LOGN) | ((2*j+1)*16 + w*4 + q);

  float scL[8], shL[8], scL2[8], shL2[8], scM[8], shM[8];
  #pragma unroll
  for(int c=0;c<8;c++){
    load_fin(fin, ST_L1, b,c, scL[c], shL[c]);
    load_fin(fin, ST_L2, b,c, scL2[c],shL2[c]);
    load_fin(fin, ST_M1, b,c, scM[c], shM[c]);
  }
  U16 bu; bu.u = make_uint4(0,0,0,0);
  if(q < 2){
    const float* wr = Wa2 + l15*16 + q*8;
    float4 w0 = *(const float4*)(wr);
    float4 w1 = *(const float4*)(wr+4);
    bu.u = make_uint4(pkbf(w0.x,w0.y), pkbf(w0.z,w0.w), pkbf(w1.x,w1.y), pkbf(w1.z,w1.w));
  }
  float wmr[16];
  {
    const float4* wp = (const float4*)(Wm2 + l15*16);
    float4 m0=wp[0], m1=wp[1], m2=wp[2], m3=wp[3];
    wmr[0]=m0.x; wmr[1]=m0.y; wmr[2]=m0.z; wmr[3]=m0.w;
    wmr[4]=m1.x; wmr[5]=m1.y; wmr[6]=m1.z; wmr[7]=m1.w;
    wmr[8]=m2.x; wmr[9]=m2.y; wmr[10]=m2.z; wmr[11]=m2.w;
    wmr[12]=m3.x; wmr[13]=m3.y; wmr[14]=m3.z; wmr[15]=m3.w;
  }
  float bm2v = bm2[l15];

  __shared__ unsigned char SB[4][2*WV_BYTES];
  __shared__ float lst[8];
  if(tid<8) lst[tid]=0.f;
  char* wb = (char*)SB[w];

  char* recB = (char*)(ws + RECB_OFF);
  char* pairb = (char*)(ws + PAIR_OFF);
  float* prem2 = ws + PREM2_OFF;

  // ---- phase A: both tiles, gathers up front ----
  int idxT[2];
  #pragma unroll
  for(int t=0;t<2;t++)
    idxT[t] = __builtin_nontemporal_load(nidx + (size_t)pAt[t]*KNB + l15);
  uint4 pm1T[2]; u32x4 lpT[2]; float4 nbT[2], ctT[2];
  #pragma unroll
  for(int t=0;t<2;t++){
    const char* rp = recB + ((size_t)((b<<LOGN)|idxT[t]))*32;
    pm1T[t] = *(const uint4*)(rp);
    if constexpr (PAIR){
      lpT[t] = __builtin_nontemporal_load(
          (const u32x4*)(pairb + ((size_t)pAt[t]*KNB + l15)*16));
    } else {
      nbT[t] = *(const float4*)(rp + 16);
      ctT[t] = *(const float4*)(recB + (size_t)pAt[t]*32 + 16);
    }
  }

  #pragma unroll
  for(int t=0;t<2;t++){
    float fx2[8];
    if constexpr (PAIR){
      u32x4 lp = lpT[t];
      fx2[0]=lrelu(blo(lp.x)*scL2[0]+shL2[0]); fx2[1]=lrelu(bhi(lp.x)*scL2[1]+shL2[1]);
      fx2[2]=lrelu(blo(lp.y)*scL2[2]+shL2[2]); fx2[3]=lrelu(bhi(lp.y)*scL2[3]+shL2[3]);
      fx2[4]=lrelu(blo(lp.z)*scL2[4]+shL2[4]); fx2[5]=lrelu(bhi(lp.z)*scL2[5]+shL2[5]);
      fx2[6]=lrelu(blo(lp.w)*scL2[6]+shL2[6]); fx2[7]=lrelu(bhi(lp.w)*scL2[7]+shL2[7]);
    } else {
      float4 nb = nbT[t], ct = ctT[t];
      float rx=nb.x-ct.x, ry=nb.y-ct.y, rz=nb.z-ct.z;
      float dd = __builtin_amdgcn_sqrtf(rx*rx+ry*ry+rz*rz);
      float fr[10] = {dd,rx,ry,rz,ct.x,ct.y,ct.z,nb.x,nb.y,nb.z};
      float fx[8];
      #pragma unroll
      for(int c=0;c<8;c++){
        float v = bl1[c];
        #pragma unroll
        for(int jj=0;jj<10;jj++) v += WL1[c*10+jj]*fr[jj];
        fx[c] = lrelu(v*scL[c]+shL[c]);
      }
      #pragma unroll
      for(int c=0;c<8;c++){
        float v = b2[c];
        #pragma unroll
        for(int jj=0;jj<8;jj++) v += W2[c*8+jj]*fx[jj];
        fx2[c] = lrelu(v*scL2[c]+shL2[c]);
      }
    }
    uint4 pm1 = pm1T[t];
    float xn[8];
    xn[0]=lrelu(blo(pm1.x)*scM[0]+shM[0]); xn[1]=lrelu(bhi(pm1.x)*scM[1]+shM[1]);
    xn[2]=lrelu(blo(pm1.y)*scM[2]+shM[2]); xn[3]=lrelu(bhi(pm1.y)*scM[3]+shM[3]);
    xn[4]=lrelu(blo(pm1.z)*scM[4]+shM[4]); xn[5]=lrelu(bhi(pm1.z)*scM[5]+shM[5]);
    xn[6]=lrelu(blo(pm1.w)*scM[6]+shM[6]); xn[7]=lrelu(bhi(pm1.w)*scM[7]+shM[7]);

    uint4 d0 = make_uint4(pkbf(xn[0],xn[1]), pkbf(xn[2],xn[3]), pkbf(xn[4],xn[5]), pkbf(xn[6],xn[7]));
    uint4 d1 = make_uint4(pkbf(fx2[0],fx2[1]), pkbf(fx2[2],fx2[3]), pkbf(fx2[4],fx2[5]), pkbf(fx2[6],fx2[7]));
    char* base = wb + t*WV_BYTES + XB_OFF + q*256 + rowadr(l15);
    *(uint4*)(base)        = d0;
    *(uint4*)(base + 1024) = d1;
  }

  wave_fence();

  f32x4 cz = {0.f,0.f,0.f,0.f};
  int rxf = q & 2;
  #pragma unroll
  for(int t=0;t<2;t++){
    const char* xc = wb + t*WV_BYTES + XB_OFF + (l15>>3)*1024 + (l15&7)*2;
    #pragma unroll
    for(int pt=0; pt<4; pt++){
      U16 afr; afr.u = make_uint4(0,0,0,0);
      if(q < 2) afr.u = *(const uint4*)(wb + t*WV_BYTES + XB_OFF + q*1024 + pt*256 + rowadr(l15));
      f32x4 cf = __builtin_amdgcn_mfma_f32_16x16x32_bf16(afr.s, bu.s, cz, 0,0,0);
      float mx = fmaxf(fmaxf(cf[0],cf[1]), fmaxf(cf[2],cf[3]));
      mx = x16max(mx); mx = x32max(mx);
      float pe0=__expf(cf[0]-mx), pe1=__expf(cf[1]-mx), pe2=__expf(cf[2]-mx), pe3=__expf(cf[3]-mx);
      float ps = pe0+pe1+pe2+pe3;
      ps = s16(ps); ps = s32(ps);
      const char* xe = xc + pt*256 + 64*q;
      float acc = pe0*bfu(*(const unsigned short*)(xe + 16*(0^rxf)))
                + pe1*bfu(*(const unsigned short*)(xe + 16*(1^rxf)))
                + pe2*bfu(*(const unsigned short*)(xe + 16*(2^rxf)))
                + pe3*bfu(*(const unsigned short*)(xe + 16*(3^rxf)));
      acc = s16(acc); acc = s32(acc);
      float agg = acc*__builtin_amdgcn_rcpf(ps);
      if(q==0) *(float*)(wb + t*WV_BYTES + AG_OFF + (pt*16+l15)*4) = agg;
    }
  }

  wave_fence();

  // ---- phase D: both tiles ----
  float m2as=0.f, m2aq=0.f;
  #pragma unroll
  for(int t=0;t<2;t++){
    float v;
    {
      const float4* agp = (const float4*)(wb + t*WV_BYTES + AG_OFF + q*64);
      float4 A0=agp[0], A1=agp[1], A2=agp[2], A3=agp[3];
      v = bm2v;
      v += wmr[0]*A0.x + wmr[1]*A0.y + wmr[2]*A0.z + wmr[3]*A0.w;
      v += wmr[4]*A1.x + wmr[5]*A1.y + wmr[6]*A1.z + wmr[7]*A1.w;
      v += wmr[8]*A2.x + wmr[9]*A2.y + wmr[10]*A2.z + wmr[11]*A2.w;
      v += wmr[12]*A3.x + wmr[13]*A3.y + wmr[14]*A3.z + wmr[15]*A3.w;
    }
    __builtin_nontemporal_store(v, prem2 + (size_t)pAt[t]*16 + l15);
    m2as += v; m2aq += v*v;
  }

  float s = s16(m2as); s = s32(s); s += __shfl_xor(s,1); s += __shfl_xor(s,2);
  float qq = s16(m2aq); qq = s32(qq); qq += __shfl_xor(qq,1); qq += __shfl_xor(qq,2);

  __syncthreads();
  if(lane < 16 && (lane&3)==0){
    atomicAdd(&lst[(lane>>2)*2],   s);
    atomicAdd(&lst[(lane>>2)*2+1], qq);
  }
  __syncthreads();
  if(tid<8){
    int g=(tid>>1)&3, wsel=tid&1;
    atomicAdd(ws + ((ST_M2*4+b)*4+g)*128 + wsel*64 + (bid&63), lst[tid]);
  }
}

// ---------------- K4: stats of mlp2 output ----------------
__global__ __launch_bounds__(256) void k4(
    const float* __restrict__ Wo,  const float* __restrict__ bo,
    float* __restrict__ ws){
  const float* fin = ws + FIN_OFF;
  int b=blockIdx.y; int n=blockIdx.x*256+threadIdx.x; int p=(b<<LOGN)|n;
  float scM[16], shM[16];
  #pragma unroll
  for(int c=0;c<16;c++) load_fin(fin, ST_M2, b, c, scM[c], shM[c]);
  const f32x4* pm = (const f32x4*)(ws + PREM2_OFF) + (size_t)p*4;
  float fa[16];
  #pragma unroll
  for(int i=0;i<4;i++){
    f32x4 v4 = __builtin_nontemporal_load(pm + i);
    fa[i*4+0]=lrelu(v4.x*scM[i*4+0]+shM[i*4+0]);
    fa[i*4+1]=lrelu(v4.y*scM[i*4+1]+shM[i*4+1]);
    fa[i*4+2]=lrelu(v4.z*scM[i*4+2]+shM[i*4+2]);
    fa[i*4+3]=lrelu(v4.w*scM[i*4+3]+shM[i*4+3]);
  }
  float sos[4]={0,0,0,0}, soq[4]={0,0,0,0};
  #pragma unroll
  for(int o=0;o<32;o++){
    float v=bo[o];
    #pragma unroll
    for(int c=0;c<16;c++) v += Wo[o*16+c]*fa[c];
    sos[o>>3]+=v; soq[o>>3]+=v*v;
  }
  __shared__ float lst[8];
  if(threadIdx.x<8) lst[threadIdx.x]=0.f;
  __syncthreads();
  int lane = threadIdx.x & 63;
  #pragma unroll
  for(int g=0;g<4;g++){
    float a=wred(sos[g]), q=wred(soq[g]);
    if(lane==0){ atomicAdd(&lst[g*2],a); atomicAdd(&lst[g*2+1],q); }
  }
  __syncthreads();
  if(threadIdx.x<8){
    int g=(threadIdx.x>>1)&3, w=threadIdx.x&1;
    atomicAdd(ws + ((ST_OUT*4+b)*4+g)*128 + w*64 + (blockIdx.x&63), lst[threadIdx.x]);
  }
}

// ---------------- K5: final out ----------------
__global__ __launch_bounds__(256) void k5(
    const float* __restrict__ feat,
    const float* __restrict__ Wo,  const float* __restrict__ bo,
    const float* __restrict__ Wsk, const float* __restrict__ bsk,
    const float* __restrict__ ws, float* __restrict__ out){
  const float* fin = ws + FIN_OFF;
  int b=blockIdx.y; int n=blockIdx.x*256+threadIdx.x; int p=(b<<LOGN)|n;
  float scM[16], shM[16];
  #pragma unroll
  for(int c=0;c<16;c++) load_fin(fin, ST_M2, b, c, scM[c], shM[c]);
  const f32x4* pm = (const f32x4*)(ws + PREM2_OFF) + (size_t)p*4;
  float fa[16];
  #pragma unroll
  for(int i=0;i<4;i++){
    f32x4 v4 = __builtin_nontemporal_load(pm + i);
    fa[i*4+0]=lrelu(v4.x*scM[i*4+0]+shM[i*4+0]);
    fa[i*4+1]=lrelu(v4.y*scM[i*4+1]+shM[i*4+1]);
    fa[i*4+2]=lrelu(v4.z*scM[i*4+2]+shM[i*4+2]);
    fa[i*4+3]=lrelu(v4.w*scM[i*4+3]+shM[i*4+3]);
  }
  float f[8];
  #pragma unroll
  for(int c=0;c<8;c++) f[c]=__builtin_nontemporal_load(feat + (b*8+c)*NPTS + n);
  #pragma unroll
  for(int o=0;o<32;o++){
    float to = bo[o];
    #pragma unroll
    for(int c=0;c<16;c++) to += Wo[o*16+c]*fa[c];
    float ts = bsk[o];
    #pragma unroll
    for(int j=0;j<8;j++) ts += Wsk[o*8+j]*f[j];
    float scO, shO, scS, shS;
    load_fin(fin, ST_OUT,  b, o, scO, shO);
    load_fin(fin, ST_SKIP, b, o, scS, shS);
    float v = to*scO+shO + ts*scS+shS;
    __builtin_nontemporal_store(lrelu(v), out + (size_t)(b*32+o)*NPTS + n);
  }
}

extern "C" void kernel_launch(void* const* d_in, const int* in_sizes, int n_in,
                              void* d_out, int out_size, void* d_ws, size_t ws_size,
                              hipStream_t stream){
  (void)in_sizes; (void)n_in; (void)out_size;
  const float* feat=(const float*)d_in[0];
  const float* xyz =(const float*)d_in[1];
  const int*   nidx=(const int*)d_in[2];
  const float* W1  =(const float*)d_in[3];
  const float* b1  =(const float*)d_in[4];
  const float* g1  =(const float*)d_in[5];
  const float* be1 =(const float*)d_in[6];
  const float* WL1 =(const float*)d_in[7];
  const float* bl1 =(const float*)d_in[8];
  const float* gL1 =(const float*)d_in[9];
  const float* beL1=(const float*)d_in[10];
  const float* Wa1 =(const float*)d_in[11];
  const float* Wm1 =(const float*)d_in[12];
  const float* bm1 =(const float*)d_in[13];
  const float* gm1 =(const float*)d_in[14];
  const float* bem1=(const float*)d_in[15];
  const float* W2  =(const float*)d_in[16];
  const float* b2  =(const float*)d_in[17];
  const float* gL2 =(const float*)d_in[18];
  const float* beL2=(const float*)d_in[19];
  const float* Wa2 =(const float*)d_in[20];
  const float* Wm2 =(const float*)d_in[21];
  const float* bm2 =(const float*)d_in[22];
  const float* gm2 =(const float*)d_in[23];
  const float* bem2=(const float*)d_in[24];
  const float* Wo  =(const float*)d_in[25];
  const float* bo  =(const float*)d_in[26];
  const float* go  =(const float*)d_in[27];
  const float* beo =(const float*)d_in[28];
  const float* Wsk =(const float*)d_in[29];
  const float* bsk =(const float*)d_in[30];
  const float* gsk =(const float*)d_in[31];
  const float* besk=(const float*)d_in[32];
  float* ws=(float*)d_ws;
  float* out=(float*)d_out;

  bool usePair = (ws_size >= NEED_BYTES);

  hipMemsetAsync(d_ws, 0, STAT_F*sizeof(float), stream);
  k_pack<<<dim3(1024),dim3(256),0,stream>>>(xyz, ws);
  k1<<<dim3(1024),dim3(256),0,stream>>>(feat, nidx, W1,b1, Wsk,bsk, WL1,bl1, ws);
  kfA<<<dim3(3),dim3(128),0,stream>>>(ws, g1,be1, gL1,beL1, gsk,besk);
  if(usePair)
    k2<true><<<dim3(8192),dim3(256),0,stream>>>(nidx, WL1,bl1, Wa1, Wm1,bm1, W2,b2, ws);
  else
    k2<false><<<dim3(8192),dim3(256),0,stream>>>(nidx, WL1,bl1, Wa1, Wm1,bm1, W2,b2, ws);
  kfB<<<dim3(2),dim3(128),0,stream>>>(ws, gm1,bem1, gL2,beL2);
  if(usePair)
    k3<true><<<dim3(8192),dim3(256),0,stream>>>(nidx, WL1,bl1, W2,b2, Wa2, Wm2,bm2, ws);
  else
    k3<false><<<dim3(8192),dim3(256),0,stream>>>(nidx, WL1,bl1, W2,b2, Wa2, Wm2,bm2, ws);
  kfC<<<dim3(1),dim3(128),0,stream>>>(ws, gm2,bem2);
  k4<<<dim3(256,4),dim3(256),0,stream>>>(Wo,bo, ws);
  kfD<<<dim3(1),dim3(128),0,stream>>>(ws, go,beo);
  k5<<<dim3(256,4),dim3(256),0,stream>>>(feat, Wo,bo, Wsk,bsk, ws, out);
}